// Round 1
// 1540.548 us; speedup vs baseline: 1.2151x; 1.2151x over previous
//
#include <hip/hip_runtime.h>
#include <hip/hip_bf16.h>
#include <stdint.h>
#include <stddef.h>

// TFT block on MI355X. B=64 T=384 V=12 D=256 H=4 DK=64.
// R4: graph restructure. (1) fg_W1+fg_Ws fused into one N=384 GEMM (one x pass).
// (2) W2@Wg precombined on device -> removes 14 GEMM dispatches.
// (3) sv chain batched over v (Z=2 groups of GEMMs, paired selacc).
typedef __bf16 bf16;
typedef __bf16 bf16x8 __attribute__((ext_vector_type(8)));
typedef float  f32x4  __attribute__((ext_vector_type(4)));

#define BTR 24576   // B*T rows
#define EPI_BIAS  1
#define EPI_CVEC  2
#define EPI_ELU   4
#define EPI_ATTN  8
#define EPI_SPLIT 16  // cols >= 256: bias only (no cvec, no ELU)

// ---------------- 128x128 tile bf16 MFMA GEMM, C[m][n] = sum_k A[m][k]*Bt[n][k] ----------------
// AF32: A operand is float32 in global (converted to bf16 at staging). CF32: C stored as float.
// grid = (N/128, M/128, Z). batch: h=z/zdiv, b=z%zdiv. bias advances z*sBias.
template<int EPI, bool AF32, bool CF32>
__global__ __launch_bounds__(256, 2)
void gemm_kernel(const void* __restrict__ Av, int lda, long sAh, long sAb,
                 const bf16* __restrict__ Bt, int ldb, long sBh, long sBb,
                 void* __restrict__ Cv, int ldc, long sC,
                 int K, int zdiv,
                 const float* __restrict__ bias, const float* __restrict__ cvec,
                 long sBias)
{
  __shared__ __align__(16) bf16 As[128 * 32];
  __shared__ __align__(16) bf16 Bs[128 * 32];

  const int tid  = threadIdx.x;
  const int wave = tid >> 6, lane = tid & 63;
  const int wr = wave >> 1, wc = wave & 1;         // 2x2 waves, 64x64 each
  const int quad = lane >> 4, l16 = lane & 15;

  const int z  = blockIdx.z;
  const int hh = z / zdiv, bb = z % zdiv;
  const float* AbF = nullptr; const bf16* AbH = nullptr;
  if constexpr (AF32) AbF = (const float*)Av + (long)hh * sAh + (long)bb * sAb;
  else                AbH = (const bf16*)Av  + (long)hh * sAh + (long)bb * sAb;
  const bf16* Bb = Bt + (long)hh * sBh + (long)bb * sBb;
  float* CbF = nullptr; bf16* CbH = nullptr;
  if constexpr (CF32) CbF = (float*)Cv + (long)z * sC;
  else                CbH = (bf16*)Cv  + (long)z * sC;

  const int rowBase = blockIdx.y * 128;
  const int colBase = blockIdx.x * 128;

  f32x4 acc[4][4];
#pragma unroll
  for (int i = 0; i < 4; ++i)
#pragma unroll
    for (int j = 0; j < 4; ++j) { acc[i][j][0]=0.f; acc[i][j][1]=0.f; acc[i][j][2]=0.f; acc[i][j][3]=0.f; }

  const int r0 = tid >> 2, kc = tid & 3;           // bf16-A / B decode: 16B chunks, 4 per 32-elem row
  const int r1 = tid >> 1, kh = (tid & 1) * 16;    // f32-A decode: 64B half-rows
  const int arow = (wr * 64 + l16) * 32 + quad * 8;
  const int brow = (wc * 64 + l16) * 32 + quad * 8;

  for (int k0 = 0; k0 < K; k0 += 32) {
    bf16x8 a0, a1;
    if constexpr (AF32) {
      const float* p = AbF + (size_t)(rowBase + r1) * lda + k0 + kh;
      f32x4 f0 = *(const f32x4*)(p);
      f32x4 f1 = *(const f32x4*)(p + 4);
      f32x4 f2 = *(const f32x4*)(p + 8);
      f32x4 f3 = *(const f32x4*)(p + 12);
#pragma unroll
      for (int e = 0; e < 4; ++e) {
        a0[e] = (bf16)f0[e]; a0[4 + e] = (bf16)f1[e];
        a1[e] = (bf16)f2[e]; a1[4 + e] = (bf16)f3[e];
      }
    } else {
      a0 = *(const bf16x8*)(AbH + (size_t)(rowBase + r0)      * lda + k0 + kc * 8);
      a1 = *(const bf16x8*)(AbH + (size_t)(rowBase + 64 + r0) * lda + k0 + kc * 8);
    }
    bf16x8 b0 = *(const bf16x8*)(Bb + (size_t)(colBase + r0)      * ldb + k0 + kc * 8);
    bf16x8 b1 = *(const bf16x8*)(Bb + (size_t)(colBase + 64 + r0) * ldb + k0 + kc * 8);
    __syncthreads();   // previous iteration's ds_reads complete before overwrite
    if constexpr (AF32) {
      *(bf16x8*)(As + r1 * 32 + kh)     = a0;
      *(bf16x8*)(As + r1 * 32 + kh + 8) = a1;
    } else {
      *(bf16x8*)(As +        r0 * 32 + kc * 8) = a0;
      *(bf16x8*)(As + 2048 + r0 * 32 + kc * 8) = a1;
    }
    *(bf16x8*)(Bs +        r0 * 32 + kc * 8) = b0;
    *(bf16x8*)(Bs + 2048 + r0 * 32 + kc * 8) = b1;
    __syncthreads();

    bf16x8 af[4], bfv[4];
#pragma unroll
    for (int mi = 0; mi < 4; ++mi) af[mi]  = *(const bf16x8*)(As + arow + mi * 512);
#pragma unroll
    for (int ni = 0; ni < 4; ++ni) bfv[ni] = *(const bf16x8*)(Bs + brow + ni * 512);
#pragma unroll
    for (int mi = 0; mi < 4; ++mi)
#pragma unroll
      for (int ni = 0; ni < 4; ++ni)
        acc[mi][ni] = __builtin_amdgcn_mfma_f32_16x16x32_bf16(af[mi], bfv[ni], acc[mi][ni], 0, 0, 0);
  }

  // epilogue. C/D layout: col = lane&15, row = quad*4 + reg  [m89-verified]
  const bool act = !(EPI & EPI_SPLIT) || (colBase < 256);   // block-uniform
  const int bctx = (EPI & EPI_CVEC) ? (rowBase / 384) : 0;  // 128-row tile never crosses a b boundary
  const float* bp = bias + (size_t)z * sBias;
#pragma unroll
  for (int mi = 0; mi < 4; ++mi) {
#pragma unroll
    for (int ni = 0; ni < 4; ++ni) {
      const int row0 = rowBase + wr * 64 + mi * 16 + quad * 4;
      const int col  = colBase + wc * 64 + ni * 16 + l16;
      float bv = (EPI & EPI_BIAS) ? bp[col] : 0.f;
      float cv = ((EPI & EPI_CVEC) && act) ? cvec[bctx * 256 + col] : 0.f;
#pragma unroll
      for (int r = 0; r < 4; ++r) {
        float v = acc[mi][ni][r] + bv + cv;
        if ((EPI & EPI_ELU) && act) v = v > 0.f ? v : __expf(v) - 1.f;
        if (EPI & EPI_ATTN) { v *= 0.125f; if (col > row0 + r) v = -1e9f; }
        if constexpr (CF32) CbF[(size_t)(row0 + r) * ldc + col] = v;
        else                CbH[(size_t)(row0 + r) * ldc + col] = (bf16)v;
      }
    }
  }
}

// ---------------- prep: weight transposes / pads / plain casts (f32 -> bf16), one launch ----------------
__global__ void prep_kernel(
    const float* fgW1, const float* fgWs, const float* fgW2, const float* fgWg,
    const float* fgb1, const float* fgbs,
    const float* svW1, const float* svWg, const float* svW2,
    const float* enW1, const float* enWg, const float* enW2,
    const float* Wq, const float* Wk, const float* Wv, const float* Wo,
    bf16* fgW1WsT, bf16* fgWgPT, bf16* fgW2C, float* bias384,
    bf16* svW1T, bf16* svWgT, bf16* svW2C,
    bf16* enW1T, bf16* enWgT, bf16* enW2C,
    bf16* WqkvT, bf16* WoT)
{
  long i = (long)blockIdx.x * 256 + threadIdx.x;
  if (i < 1179648) {               // fused [W1 | Ws(pad12->128)] transposed: 384 x 3072
    int n = i / 3072, k = i % 3072; float v;
    if (n < 256) v = fgW1[(size_t)k * 256 + n];
    else { int nn = n - 256; v = (nn < 12) ? fgWs[(size_t)k * 12 + nn] : 0.f; }
    fgW1WsT[i] = (bf16)v; return; } i -= 1179648;
  if (i < 32768)  { int n = i >> 8, k = i & 255; fgWgPT[i] = (n < 24) ? (bf16)fgWg[k * 24 + n] : (bf16)0.f; return; } i -= 32768;
  if (i < 65536)  { fgW2C[i] = (bf16)fgW2[i]; return; } i -= 65536;     // plain [k2][k]
  if (i < 384)    { bias384[i] = (i < 256) ? fgb1[i] : ((i < 268) ? fgbs[i - 256] : 0.f); return; } i -= 384;
  if (i < 786432) { long v = i >> 16, r = i & 65535; int n = r >> 8, k = r & 255; svW1T[i] = (bf16)svW1[(v << 16) + k * 256 + n]; return; } i -= 786432;
  if (i < 1572864){ long v = i >> 17, r = i & 131071; int n = r >> 8, k = r & 255; svWgT[i] = (bf16)svWg[(v << 17) + k * 512 + n]; return; } i -= 1572864;
  if (i < 786432) { svW2C[i] = (bf16)svW2[i]; return; } i -= 786432;    // plain per-v [k2][k]
  if (i < 65536)  { int n = i >> 8, k = i & 255; enW1T[i] = (bf16)enW1[k * 256 + n]; return; } i -= 65536;
  if (i < 131072) { int n = i >> 8, k = i & 255; enWgT[i] = (bf16)enWg[k * 512 + n]; return; } i -= 131072;
  if (i < 65536)  { enW2C[i] = (bf16)enW2[i]; return; } i -= 65536;     // plain
  if (i < 163840) { int n = i >> 8, k = i & 255; float val;
                    if (n < 256)      val = Wq[(n >> 6) * 16384 + k * 64 + (n & 63)];
                    else if (n < 512) { int nn = n - 256; val = Wk[(nn >> 6) * 16384 + k * 64 + (nn & 63)]; }
                    else if (n < 576) val = Wv[k * 64 + (n - 512)];
                    else              val = 0.f;
                    WqkvT[i] = (bf16)val; return; } i -= 163840;
  if (i < 16384)  { int n = i >> 6, k = i & 63; WoT[i] = (bf16)Wo[k * 256 + n]; }
}

// ---------------- fused bias: bF[n] = b2 @ Wg [,n] + bg[n]  (f32, exact) ----------------
__global__ void biasfuse_kernel(const float* fgb2, const float* fgWg, const float* fgbg,
                                const float* svb2, const float* svWg, const float* svbg,
                                const float* enb2, const float* enWg, const float* enbg,
                                float* fgBF, float* svBF, float* enBF)
{
  int i = blockIdx.x * 256 + threadIdx.x;
  if (i < 128) {
    float s = 0.f;
    if (i < 24) { s = fgbg[i]; for (int k = 0; k < 256; ++k) s += fgb2[k] * fgWg[k * 24 + i]; }
    fgBF[i] = s; return; } i -= 128;
  if (i < 6144) {
    int v = i >> 9, n = i & 511;
    float s = svbg[v * 512 + n];
    const float* W = svWg + (size_t)v * 131072;
    const float* b2 = svb2 + v * 256;
    for (int k = 0; k < 256; ++k) s += b2[k] * W[k * 512 + n];
    svBF[i] = s; return; } i -= 6144;
  if (i < 512) {
    float s = enbg[i];
    for (int k = 0; k < 256; ++k) s += enb2[k] * enWg[k * 512 + i];
    enBF[i] = s; }
}

// ---------------- cvec[b][n] = context[b] @ Wc  (fg / en), all f32 ----------------
__global__ void cvec_kernel(const float* __restrict__ ctx, const float* __restrict__ WcFg,
                            const float* __restrict__ WcEn, float* __restrict__ outFg,
                            float* __restrict__ outEn) {
  int b = blockIdx.x, n = threadIdx.x;
  const float* Wc = blockIdx.y ? WcEn : WcFg;
  float* o = blockIdx.y ? outEn : outFg;
  float acc = 0.f;
  for (int d = 0; d < 256; ++d) acc += ctx[b * 256 + d] * Wc[d * 256 + n];
  o[b * 256 + n] = acc;
}

// ---------------- lnsm12: gate + w = softmax(LN(skip + gated)) over V=12 (gate12 fused in) ----------------
__global__ void lnsm12_kernel(const bf16* __restrict__ B384, const bf16* __restrict__ GP,
                              const float* __restrict__ lng, const float* __restrict__ lnb,
                              float* __restrict__ w) {
  int r = blockIdx.x * 256 + threadIdx.x;
  if (r >= BTR) return;
  float y[12]; float m = 0.f;
#pragma unroll
  for (int j = 0; j < 12; ++j) {
    float a = (float)GP[(size_t)r * 128 + j];
    float g = (float)GP[(size_t)r * 128 + 12 + j];
    float gated = a / (1.f + __expf(-g));
    y[j] = (float)B384[(size_t)r * 384 + 256 + j] + gated; m += y[j];
  }
  m *= (1.f / 12.f);
  float var = 0.f;
#pragma unroll
  for (int j = 0; j < 12; ++j) { float d = y[j] - m; var += d * d; }
  var *= (1.f / 12.f);
  float rstd = rsqrtf(var + 1e-5f);
  float mx = -1e30f;
#pragma unroll
  for (int j = 0; j < 12; ++j) { y[j] = (y[j] - m) * rstd * lng[j] + lnb[j]; mx = fmaxf(mx, y[j]); }
  float s = 0.f;
#pragma unroll
  for (int j = 0; j < 12; ++j) { y[j] = __expf(y[j] - mx); s += y[j]; }
  float inv = 1.f / s;
#pragma unroll
  for (int j = 0; j < 12; ++j) w[r * 12 + j] = y[j] * inv;
}

// ---------------- block (256-thr) reduce of two sums ----------------
__device__ __forceinline__ void block_sum2(float a, float b, float& oa, float& ob) {
#pragma unroll
  for (int o = 32; o; o >>= 1) { a += __shfl_xor(a, o); b += __shfl_xor(b, o); }
  __shared__ float ra[4], rb[4];
  int w = threadIdx.x >> 6;
  if ((threadIdx.x & 63) == 0) { ra[w] = a; rb[w] = b; }
  __syncthreads();
  oa = ra[0] + ra[1] + ra[2] + ra[3];
  ob = rb[0] + rb[1] + rb[2] + rb[3];
  __syncthreads();
}

// ---------------- per-variable GRN tail for a PAIR of vars: gate + LN + weighted acc ----------------
__global__ __launch_bounds__(256)
void selacc2_kernel(const bf16* __restrict__ G, const float* __restrict__ x,
                    const float* __restrict__ w, const float* __restrict__ lng,
                    const float* __restrict__ lnb, float* __restrict__ sel,
                    bf16* __restrict__ selb, int v0, int isFirst, int isLast) {
  int r = blockIdx.x, d = threadIdx.x;
  float acc = isFirst ? 0.f : sel[(size_t)r * 256 + d];
#pragma unroll
  for (int vv = 0; vv < 2; ++vv) {
    int v = v0 + vv;
    const bf16* g = G + (size_t)vv * ((size_t)BTR * 512) + (size_t)r * 512;
    float a  = (float)g[d];
    float gg = (float)g[256 + d];
    float gated = a / (1.f + __expf(-gg));
    float y = x[(size_t)r * 3072 + v * 256 + d] + gated;
    float s1, s2;
    block_sum2(y, y * y, s1, s2);
    float mean = s1 * (1.f / 256.f);
    float var  = s2 * (1.f / 256.f) - mean * mean;
    float val  = (y - mean) * rsqrtf(var + 1e-5f) * lng[v * 256 + d] + lnb[v * 256 + d];
    acc += w[r * 12 + v] * val;
  }
  if (isLast) selb[(size_t)r * 256 + d] = (bf16)acc;
  else        sel[(size_t)r * 256 + d] = acc;
}

// ---------------- enrichment GRN tail: gating + LN -> enr (bf16) ----------------
__global__ __launch_bounds__(256)
void enrln_kernel(const bf16* __restrict__ G, const bf16* __restrict__ skip,
                  const float* __restrict__ lng, const float* __restrict__ lnb,
                  bf16* __restrict__ out) {
  int r = blockIdx.x, d = threadIdx.x;
  float a = (float)G[(size_t)r * 512 + d];
  float g = (float)G[(size_t)r * 512 + 256 + d];
  float gated = a / (1.f + __expf(-g));
  float y = (float)skip[(size_t)r * 256 + d] + gated;
  float s1, s2;
  block_sum2(y, y * y, s1, s2);
  float mean = s1 * (1.f / 256.f);
  float var = s2 * (1.f / 256.f) - mean * mean;
  float norm = (y - mean) * rsqrtf(var + 1e-5f);
  out[(size_t)r * 256 + d] = (bf16)(norm * lng[d] + lnb[d]);
}

// ---------------- Pbar[b,q,:] = (1/4) sum_h softmax(S[h,b,q,:]) ----------------
__global__ __launch_bounds__(384)
void softmax_avg_kernel(const bf16* __restrict__ S, bf16* __restrict__ P) {
  const int bq = blockIdx.x;
  const int b = bq / 384, q = bq % 384;
  const int j = threadIdx.x;
  const int w = j >> 6;
  __shared__ float red[6];
  float pb = 0.f;
  for (int h = 0; h < 4; ++h) {
    float s = (float)S[((size_t)((h * 64 + b) * 384 + q)) * 384 + j];
    float m = s;
#pragma unroll
    for (int o = 32; o; o >>= 1) m = fmaxf(m, __shfl_xor(m, o));
    if ((j & 63) == 0) red[w] = m;
    __syncthreads();
    m = fmaxf(fmaxf(fmaxf(red[0], red[1]), fmaxf(red[2], red[3])), fmaxf(red[4], red[5]));
    __syncthreads();
    float e = __expf(s - m);
    float l = e;
#pragma unroll
    for (int o = 32; o; o >>= 1) l += __shfl_xor(l, o);
    if ((j & 63) == 0) red[w] = l;
    __syncthreads();
    l = red[0] + red[1] + red[2] + red[3] + red[4] + red[5];
    __syncthreads();
    pb += e / l;
  }
  P[(size_t)bq * 384 + j] = (bf16)(0.25f * pb);
}

// ---------------- UT[b][d][t] = U[b*384+t][d] ----------------
__global__ void transpose_u_kernel(const bf16* __restrict__ U, bf16* __restrict__ UT) {
  int t = blockIdx.x, b = blockIdx.y, d = threadIdx.x;
  UT[((size_t)b * 256 + d) * 384 + t] = U[((size_t)b * 384 + t) * 256 + d];
}

// ================= host side =================
template<int EPI, bool AF32, bool CF32>
static inline void rungemm(hipStream_t s,
    const void* A, int lda, const bf16* Bt, int ldb, void* C, int ldc,
    int M, int N, int K,
    const float* bias = nullptr, const float* cvec = nullptr,
    int Z = 1, int zdiv = 1,
    long sAh = 0, long sAb = 0, long sBh = 0, long sBb = 0, long sC = 0, long sBias = 0)
{
  dim3 grid(N / 128, M / 128, Z);
  gemm_kernel<EPI, AF32, CF32><<<grid, 256, 0, s>>>(A, lda, sAh, sAb, Bt, ldb, sBh, sBb, C, ldc, sC, K, zdiv, bias, cvec, sBias);
}

extern "C" void kernel_launch(void* const* d_in, const int* in_sizes, int n_in,
                              void* d_out, int out_size, void* d_ws, size_t ws_size,
                              hipStream_t stream)
{
  (void)in_sizes; (void)n_in; (void)out_size;
  const float* x      = (const float*)d_in[0];
  const float* ctx    = (const float*)d_in[1];
  const float* fg_W1  = (const float*)d_in[2];
  const float* fg_b1  = (const float*)d_in[3];
  const float* fg_Wc  = (const float*)d_in[4];
  const float* fg_W2  = (const float*)d_in[5];
  const float* fg_b2  = (const float*)d_in[6];
  const float* fg_Wg  = (const float*)d_in[7];
  const float* fg_bg  = (const float*)d_in[8];
  const float* fg_Ws  = (const float*)d_in[9];
  const float* fg_bs  = (const float*)d_in[10];
  const float* fg_lng = (const float*)d_in[11];
  const float* fg_lnb = (const float*)d_in[12];
  const float* sv_W1  = (const float*)d_in[13];
  const float* sv_b1  = (const float*)d_in[14];
  const float* sv_W2  = (const float*)d_in[15];
  const float* sv_b2  = (const float*)d_in[16];
  const float* sv_Wg  = (const float*)d_in[17];
  const float* sv_bg  = (const float*)d_in[18];
  const float* sv_lng = (const float*)d_in[19];
  const float* sv_lnb = (const float*)d_in[20];
  const float* en_W1  = (const float*)d_in[21];
  const float* en_b1  = (const float*)d_in[22];
  const float* en_Wc  = (const float*)d_in[23];
  const float* en_W2  = (const float*)d_in[24];
  const float* en_b2  = (const float*)d_in[25];
  const float* en_Wg  = (const float*)d_in[26];
  const float* en_bg  = (const float*)d_in[27];
  const float* en_lng = (const float*)d_in[28];
  const float* en_lnb = (const float*)d_in[29];
  const float* Wq     = (const float*)d_in[30];
  const float* Wk     = (const float*)d_in[31];
  const float* Wv     = (const float*)d_in[32];
  const float* Wo     = (const float*)d_in[33];

  // -------- workspace layout (bytes) --------
  // weights
  static constexpr size_t OFF_FGW1WST = 0;                          // 384x3072 bf16 (W1 | Ws pad)
  static constexpr size_t OFF_FGWGPT  = OFF_FGW1WST + 2359296;      // 128x256 bf16
  static constexpr size_t OFF_FGW2C   = OFF_FGWGPT  + 65536;        // 256x256 bf16 plain
  static constexpr size_t OFF_FGW2GT  = OFF_FGW2C   + 131072;       // 128x256 bf16 combined
  static constexpr size_t OFF_BIAS384 = OFF_FGW2GT  + 65536;        // 384 f32
  static constexpr size_t OFF_FGBF    = OFF_BIAS384 + 1536;         // 128 f32
  static constexpr size_t OFF_SVW1T   = OFF_FGBF    + 512;          // 12x256x256 bf16
  static constexpr size_t OFF_SVWGT   = OFF_SVW1T   + 1572864;      // 12x512x256 bf16
  static constexpr size_t OFF_SVW2C   = OFF_SVWGT   + 3145728;      // 12x256x256 bf16 plain
  static constexpr size_t OFF_SVW2GT  = OFF_SVW2C   + 1572864;      // 12x512x256 bf16 combined
  static constexpr size_t OFF_SVBF    = OFF_SVW2GT  + 3145728;      // 12x512 f32
  static constexpr size_t OFF_ENW1T   = OFF_SVBF    + 24576;        // 256x256 bf16
  static constexpr size_t OFF_ENWGT   = OFF_ENW1T   + 131072;       // 512x256 bf16
  static constexpr size_t OFF_ENW2C   = OFF_ENWGT   + 262144;       // 256x256 bf16 plain
  static constexpr size_t OFF_ENW2GT  = OFF_ENW2C   + 131072;       // 512x256 bf16 combined
  static constexpr size_t OFF_ENBF    = OFF_ENW2GT  + 262144;       // 512 f32
  static constexpr size_t OFF_WQKVT   = OFF_ENBF    + 2048;         // 640x256 bf16
  static constexpr size_t OFF_WOT     = OFF_WQKVT   + 327680;       // 256x64 bf16
  static constexpr size_t OFF_CVECFG  = OFF_WOT     + 32768;        // 64x256 f32
  static constexpr size_t OFF_CVECEN  = OFF_CVECFG  + 65536;
  // arena with phase overlays
  static constexpr size_t REG_B       = OFF_CVECEN + 65536;         // 75497472:
                                                                    //  sv:  H1G(2xBTRx256 bf16) + GG(2xBTRx512 bf16)
                                                                    //  en:  H1EN(BTRx256) + GEN(BTRx512)
                                                                    //  att: Sbuf(256x384x384 bf16)
  static constexpr size_t REG_C       = REG_B + 75497472;           // 25165824: sel f32 | Pbar bf16
  static constexpr size_t REG_D       = REG_C + 25165824;           // 12582912: selb | U
  static constexpr size_t REG_E       = REG_D + 12582912;           // 31457280: BUF384+GPAD+wbuf | QKV
  static constexpr size_t REG_F       = REG_E + 31457280;           // 12582912: UT
  static constexpr size_t OFF_ENR     = REG_F + 12582912;           // 12582912: enr
  static constexpr size_t WS_NEEDED   = OFF_ENR + 12582912;         // ~183 MB (< 201 MB proven available)

  if (ws_size < WS_NEEDED) return;  // fail cleanly (absmax == max|ref| signals this)

  char* ws = (char*)d_ws;
  bf16*  fgW1WsT = (bf16*)(ws + OFF_FGW1WST);
  bf16*  fgWgPT  = (bf16*)(ws + OFF_FGWGPT);
  bf16*  fgW2C   = (bf16*)(ws + OFF_FGW2C);
  bf16*  fgW2gT  = (bf16*)(ws + OFF_FGW2GT);
  float* bias384 = (float*)(ws + OFF_BIAS384);
  float* fgBF    = (float*)(ws + OFF_FGBF);
  bf16*  svW1T   = (bf16*)(ws + OFF_SVW1T);
  bf16*  svWgT   = (bf16*)(ws + OFF_SVWGT);
  bf16*  svW2C   = (bf16*)(ws + OFF_SVW2C);
  bf16*  svW2gT  = (bf16*)(ws + OFF_SVW2GT);
  float* svBF    = (float*)(ws + OFF_SVBF);
  bf16*  enW1T   = (bf16*)(ws + OFF_ENW1T);
  bf16*  enWgT   = (bf16*)(ws + OFF_ENWGT);
  bf16*  enW2C   = (bf16*)(ws + OFF_ENW2C);
  bf16*  enW2gT  = (bf16*)(ws + OFF_ENW2GT);
  float* enBF    = (float*)(ws + OFF_ENBF);
  bf16*  WqkvT   = (bf16*)(ws + OFF_WQKVT);
  bf16*  WoT     = (bf16*)(ws + OFF_WOT);
  float* cvecFg  = (float*)(ws + OFF_CVECFG);
  float* cvecEn  = (float*)(ws + OFF_CVECEN);
  // overlays
  bf16*  H1G     = (bf16*)(ws + REG_B);                  // sv phase
  bf16*  GG      = (bf16*)(ws + REG_B + 25165824);
  bf16*  H1EN    = (bf16*)(ws + REG_B);                  // en phase
  bf16*  GEN     = (bf16*)(ws + REG_B + 12582912);
  bf16*  Sbuf    = (bf16*)(ws + REG_B);                  // attn phase
  float* sel     = (float*)(ws + REG_C);
  bf16*  Pbar    = (bf16*)(ws + REG_C);
  bf16*  selb    = (bf16*)(ws + REG_D);
  bf16*  U       = (bf16*)(ws + REG_D);
  bf16*  BUF384  = (bf16*)(ws + REG_E);
  bf16*  GPAD    = (bf16*)(ws + REG_E + 18874368);
  float* wbuf    = (float*)(ws + REG_E + 25165824);
  bf16*  QKV     = (bf16*)(ws + REG_E);
  bf16*  UT      = (bf16*)(ws + REG_F);
  bf16*  enr     = (bf16*)(ws + OFF_ENR);
  float* out     = (float*)d_out;

  // 1) weight prep (one launch; 4,866,432 elements)
  prep_kernel<<<19010, 256, 0, stream>>>(fg_W1, fg_Ws, fg_W2, fg_Wg, fg_b1, fg_bs,
                                         sv_W1, sv_Wg, sv_W2, en_W1, en_Wg, en_W2,
                                         Wq, Wk, Wv, Wo,
                                         fgW1WsT, fgWgPT, fgW2C, bias384,
                                         svW1T, svWgT, svW2C, enW1T, enWgT, enW2C,
                                         WqkvT, WoT);
  // 2) fused biases b2@Wg+bg (f32 exact) + context vectors
  biasfuse_kernel<<<27, 256, 0, stream>>>(fg_b2, fg_Wg, fg_bg, sv_b2, sv_Wg, sv_bg,
                                          en_b2, en_Wg, en_bg, fgBF, svBF, enBF);
  cvec_kernel<<<dim3(64, 2), 256, 0, stream>>>(ctx, fg_Wc, en_Wc, cvecFg, cvecEn);

  // 3) combined weights W2gT[n][k2] = sum_k Wg[k][n] * W2[k2][k]  (tiny GEMMs)
  rungemm<0, false, false>(stream, fgWgPT, 256, fgW2C, 256, fgW2gT, 256, 128, 256, 256);
  rungemm<0, false, false>(stream, svWgT, 256, svW2C, 256, svW2gT, 256, 512, 256, 256,
                           nullptr, nullptr, 12, 12, 0, 131072, 0, 65536, 131072);
  rungemm<0, false, false>(stream, enWgT, 256, enW2C, 256, enW2gT, 256, 512, 256, 256);

  // 4) flattened GRN: fused [h1 | skip] GEMM (ONE pass over x), then fused g GEMM, then LN+softmax
  rungemm<EPI_BIAS|EPI_CVEC|EPI_ELU|EPI_SPLIT, true, false>(
      stream, x, 3072, fgW1WsT, 3072, BUF384, 384, BTR, 384, 3072, bias384, cvecFg);
  rungemm<EPI_BIAS, false, false>(stream, BUF384, 384, fgW2gT, 256, GPAD, 128, BTR, 128, 256, fgBF);
  lnsm12_kernel<<<96, 256, 0, stream>>>(BUF384, GPAD, fg_lng, fg_lnb, wbuf);

  // 5) per-variable GRNs, batched Z=2, W2 folded into Wg; weighted sum -> sel
  for (int g = 0; g < 6; ++g) {
    rungemm<EPI_BIAS|EPI_ELU, true, false>(
        stream, x + g * 2 * 256, 3072, svW1T + g * 2 * 65536, 256, H1G, 256, BTR, 256, 256,
        sv_b1 + g * 2 * 256, nullptr, 2, 2, 0, 256, 0, 65536, (long)BTR * 256, 256);
    rungemm<EPI_BIAS, false, false>(
        stream, H1G, 256, svW2gT + (size_t)g * 2 * 131072, 256, GG, 512, BTR, 512, 256,
        svBF + g * 2 * 512, nullptr, 2, 2, 0, (long)BTR * 256, 0, 131072, (long)BTR * 512, 512);
    selacc2_kernel<<<BTR, 256, 0, stream>>>(GG, x, wbuf, sv_lng, sv_lnb, sel, selb,
                                            g * 2, g == 0, g == 5);
  }

  // 6) enrichment GRN (W2 folded)
  rungemm<EPI_BIAS|EPI_CVEC|EPI_ELU, false, false>(stream, selb, 256, enW1T, 256, H1EN, 256, BTR, 256, 256, en_b1, cvecEn);
  rungemm<EPI_BIAS, false, false>(stream, H1EN, 256, enW2gT, 256, GEN, 512, BTR, 512, 256, enBF);
  enrln_kernel<<<BTR, 256, 0, stream>>>(GEN, selb, en_lng, en_lnb, enr);

  // 7) attention: QKV = enr @ [Wq|Wk|Wv] (N padded 576->640)
  rungemm<0, false, false>(stream, enr, 256, WqkvT, 256, QKV, 640, BTR, 640, 256);
  // S[h,b] = Q K^T * 0.125 with causal mask, batched z = h*64+b
  rungemm<EPI_ATTN, false, false>(stream, QKV, 640, QKV + 256, 640, Sbuf, 384, 384, 384, 64,
                                  nullptr, nullptr, 256, 64, 64, 245760L, 64, 245760L, 147456L);
  softmax_avg_kernel<<<BTR, 384, 0, stream>>>(Sbuf, Pbar);
  // U = vp @ Wo  (mean-over-heads folded: out = Pbar @ (vp@Wo))
  rungemm<0, false, false>(stream, QKV + 512, 640, WoT, 64, U, 256, BTR, 256, 64);
  transpose_u_kernel<<<dim3(384, 64), 256, 0, stream>>>(U, UT);
  // out[b] = Pbar[b] @ U[b], batched over b -> f32 d_out
  rungemm<0, false, true>(stream, Pbar, 384, UT, 384, out, 256, 384, 256, 384,
                          nullptr, nullptr, 64, 1, 147456L, 0, 98304L, 0, 98304L);
}

// Round 2
// 1417.573 us; speedup vs baseline: 1.3205x; 1.0868x over previous
//
#include <hip/hip_runtime.h>
#include <hip/hip_bf16.h>
#include <stdint.h>
#include <stddef.h>

// TFT block on MI355X. B=64 T=384 V=12 D=256 H=4 DK=64.
// R5: (1) dedicated 128x384-tile fg kernel (A-stripe read ONCE from HBM).
// (2) gate fused into W2g GEMM epilogue via column-permuted weights (GG halved).
// (3) sv chain batched Z=4 (3 groups), sel traffic cut.
typedef __bf16 bf16;
typedef __bf16 bf16x8 __attribute__((ext_vector_type(8)));
typedef float  f32x4  __attribute__((ext_vector_type(4)));

#define BTR 24576   // B*T rows
#define EPI_BIAS  1
#define EPI_CVEC  2
#define EPI_ELU   4
#define EPI_ATTN  8
#define EPI_GATE  32   // N=512 permuted pairs -> C = a*sigmoid(g), width N/2
#define EPI_PERM  64   // C-row permutation for building gate-paired weights

// col permutation: a_j -> 32*(j>>4)+(j&15), g_j -> same +16
__device__ __forceinline__ int perm512(int n) {
  return (n < 256) ? (((n >> 4) << 5) + (n & 15))
                   : ((((n - 256) >> 4) << 5) + ((n - 256) & 15) + 16);
}

// ---------------- 128x128 tile bf16 MFMA GEMM, C[m][n] = sum_k A[m][k]*Bt[n][k] ----------------
template<int EPI, bool AF32, bool CF32>
__global__ __launch_bounds__(256, 2)
void gemm_kernel(const void* __restrict__ Av, int lda, long sAh, long sAb,
                 const bf16* __restrict__ Bt, int ldb, long sBh, long sBb,
                 void* __restrict__ Cv, int ldc, long sC,
                 int K, int zdiv,
                 const float* __restrict__ bias, const float* __restrict__ cvec,
                 long sBias)
{
  __shared__ __align__(16) bf16 As[128 * 32];
  __shared__ __align__(16) bf16 Bs[128 * 32];

  const int tid  = threadIdx.x;
  const int wave = tid >> 6, lane = tid & 63;
  const int wr = wave >> 1, wc = wave & 1;         // 2x2 waves, 64x64 each
  const int quad = lane >> 4, l16 = lane & 15;

  const int z  = blockIdx.z;
  const int hh = z / zdiv, bb = z % zdiv;
  const float* AbF = nullptr; const bf16* AbH = nullptr;
  if constexpr (AF32) AbF = (const float*)Av + (long)hh * sAh + (long)bb * sAb;
  else                AbH = (const bf16*)Av  + (long)hh * sAh + (long)bb * sAb;
  const bf16* Bb = Bt + (long)hh * sBh + (long)bb * sBb;
  float* CbF = nullptr; bf16* CbH = nullptr;
  if constexpr (CF32) CbF = (float*)Cv + (long)z * sC;
  else                CbH = (bf16*)Cv  + (long)z * sC;

  const int rowBase = blockIdx.y * 128;
  const int colBase = blockIdx.x * 128;

  f32x4 acc[4][4];
#pragma unroll
  for (int i = 0; i < 4; ++i)
#pragma unroll
    for (int j = 0; j < 4; ++j) { acc[i][j][0]=0.f; acc[i][j][1]=0.f; acc[i][j][2]=0.f; acc[i][j][3]=0.f; }

  const int r0 = tid >> 2, kc = tid & 3;           // bf16-A / B decode
  const int r1 = tid >> 1, kh = (tid & 1) * 16;    // f32-A decode
  const int arow = (wr * 64 + l16) * 32 + quad * 8;
  const int brow = (wc * 64 + l16) * 32 + quad * 8;

  for (int k0 = 0; k0 < K; k0 += 32) {
    bf16x8 a0, a1;
    if constexpr (AF32) {
      const float* p = AbF + (size_t)(rowBase + r1) * lda + k0 + kh;
      f32x4 f0 = *(const f32x4*)(p);
      f32x4 f1 = *(const f32x4*)(p + 4);
      f32x4 f2 = *(const f32x4*)(p + 8);
      f32x4 f3 = *(const f32x4*)(p + 12);
#pragma unroll
      for (int e = 0; e < 4; ++e) {
        a0[e] = (bf16)f0[e]; a0[4 + e] = (bf16)f1[e];
        a1[e] = (bf16)f2[e]; a1[4 + e] = (bf16)f3[e];
      }
    } else {
      a0 = *(const bf16x8*)(AbH + (size_t)(rowBase + r0)      * lda + k0 + kc * 8);
      a1 = *(const bf16x8*)(AbH + (size_t)(rowBase + 64 + r0) * lda + k0 + kc * 8);
    }
    bf16x8 b0 = *(const bf16x8*)(Bb + (size_t)(colBase + r0)      * ldb + k0 + kc * 8);
    bf16x8 b1 = *(const bf16x8*)(Bb + (size_t)(colBase + 64 + r0) * ldb + k0 + kc * 8);
    __syncthreads();
    if constexpr (AF32) {
      *(bf16x8*)(As + r1 * 32 + kh)     = a0;
      *(bf16x8*)(As + r1 * 32 + kh + 8) = a1;
    } else {
      *(bf16x8*)(As +        r0 * 32 + kc * 8) = a0;
      *(bf16x8*)(As + 2048 + r0 * 32 + kc * 8) = a1;
    }
    *(bf16x8*)(Bs +        r0 * 32 + kc * 8) = b0;
    *(bf16x8*)(Bs + 2048 + r0 * 32 + kc * 8) = b1;
    __syncthreads();

    bf16x8 af[4], bfv[4];
#pragma unroll
    for (int mi = 0; mi < 4; ++mi) af[mi]  = *(const bf16x8*)(As + arow + mi * 512);
#pragma unroll
    for (int ni = 0; ni < 4; ++ni) bfv[ni] = *(const bf16x8*)(Bs + brow + ni * 512);
#pragma unroll
    for (int mi = 0; mi < 4; ++mi)
#pragma unroll
      for (int ni = 0; ni < 4; ++ni)
        acc[mi][ni] = __builtin_amdgcn_mfma_f32_16x16x32_bf16(af[mi], bfv[ni], acc[mi][ni], 0, 0, 0);
  }

  // epilogue. C/D layout: col = lane&15, row = quad*4 + reg  [m89-verified]
  if constexpr (EPI & EPI_GATE) {
    const float* bp = bias + (size_t)z * sBias;
#pragma unroll
    for (int mi = 0; mi < 4; ++mi) {
#pragma unroll
      for (int nj = 0; nj < 2; ++nj) {
        const int ni = nj * 2;
        const int pa = colBase + wc * 64 + ni * 16 + l16;
        const int j  = (colBase >> 1) + wc * 32 + nj * 16 + l16;
        const float ba = bp[pa], bg = bp[pa + 16];
        const int row0 = rowBase + wr * 64 + mi * 16 + quad * 4;
#pragma unroll
        for (int r = 0; r < 4; ++r) {
          float a = acc[mi][ni][r]     + ba;
          float g = acc[mi][ni + 1][r] + bg;
          CbH[(size_t)(row0 + r) * ldc + j] = (bf16)(a / (1.f + __expf(-g)));
        }
      }
    }
    return;
  }
  const int bctx = (EPI & EPI_CVEC) ? (rowBase / 384) : 0;
  const float* bp = (EPI & EPI_BIAS) ? bias + (size_t)z * sBias : nullptr;
#pragma unroll
  for (int mi = 0; mi < 4; ++mi) {
#pragma unroll
    for (int ni = 0; ni < 4; ++ni) {
      const int row0 = rowBase + wr * 64 + mi * 16 + quad * 4;
      const int col  = colBase + wc * 64 + ni * 16 + l16;
      float bv = (EPI & EPI_BIAS) ? bp[col] : 0.f;
      float cv = (EPI & EPI_CVEC) ? cvec[bctx * 256 + col] : 0.f;
#pragma unroll
      for (int r = 0; r < 4; ++r) {
        float v = acc[mi][ni][r] + bv + cv;
        if (EPI & EPI_ELU)  v = v > 0.f ? v : __expf(v) - 1.f;
        if (EPI & EPI_ATTN) { v *= 0.125f; if (col > row0 + r) v = -1e9f; }
        int srow = row0 + r;
        if constexpr (EPI & EPI_PERM) srow = perm512(srow);
        if constexpr (CF32) CbF[(size_t)srow * ldc + col] = v;
        else                CbH[(size_t)srow * ldc + col] = (bf16)v;
      }
    }
  }
}

// ---------------- fg wide kernel: 128 rows x ALL 384 cols per block, K=3072 ----------------
// A (x, f32) stripe read exactly once from HBM. B = fgW1WsT (384x3072 bf16, L2-resident).
// C = BUF384 bf16 with bias384 + cvec/ELU on cols<256 (h1), bias only on cols>=256 (skip).
__global__ __launch_bounds__(512, 2)
void fgwide_kernel(const float* __restrict__ A, const bf16* __restrict__ Bt,
                   bf16* __restrict__ C, const float* __restrict__ bias,
                   const float* __restrict__ cvec)
{
  __shared__ __align__(16) bf16 As[128 * 32];
  __shared__ __align__(16) bf16 Bs[384 * 32];
  const int tid = threadIdx.x;
  const int wave = tid >> 6, lane = tid & 63;
  const int wr = wave >> 2, wc4 = wave & 3;        // 2x4 waves: 64 rows x 96 cols each
  const int quad = lane >> 4, l16 = lane & 15;
  const int rowBase = blockIdx.x * 128;

  f32x4 acc[4][6];
#pragma unroll
  for (int i = 0; i < 4; ++i)
#pragma unroll
    for (int j = 0; j < 6; ++j) { acc[i][j][0]=0.f; acc[i][j][1]=0.f; acc[i][j][2]=0.f; acc[i][j][3]=0.f; }

  const int r1 = tid >> 2, kh = (tid & 3) * 8;     // A staging: 8 f32/thread
  const int arow = (wr * 64 + l16) * 32 + quad * 8;
  const int brow = (wc4 * 96 + l16) * 32 + quad * 8;

  for (int k0 = 0; k0 < 3072; k0 += 32) {
    const float* p = A + (size_t)(rowBase + r1) * 3072 + k0 + kh;
    f32x4 f0 = *(const f32x4*)(p);
    f32x4 f1 = *(const f32x4*)(p + 4);
    bf16x8 av;
#pragma unroll
    for (int e = 0; e < 4; ++e) { av[e] = (bf16)f0[e]; av[4 + e] = (bf16)f1[e]; }
    bf16x8 bv[3];
#pragma unroll
    for (int c = 0; c < 3; ++c) {
      int idx = c * 512 + tid;
      int rb = idx >> 2, kc = idx & 3;
      bv[c] = *(const bf16x8*)(Bt + (size_t)rb * 3072 + k0 + kc * 8);
    }
    __syncthreads();
    *(bf16x8*)(As + r1 * 32 + kh) = av;
#pragma unroll
    for (int c = 0; c < 3; ++c) {
      int idx = c * 512 + tid;
      int rb = idx >> 2, kc = idx & 3;
      *(bf16x8*)(Bs + rb * 32 + kc * 8) = bv[c];
    }
    __syncthreads();

    bf16x8 af[4], bfv[6];
#pragma unroll
    for (int mi = 0; mi < 4; ++mi) af[mi]  = *(const bf16x8*)(As + arow + mi * 512);
#pragma unroll
    for (int ni = 0; ni < 6; ++ni) bfv[ni] = *(const bf16x8*)(Bs + brow + ni * 512);
#pragma unroll
    for (int mi = 0; mi < 4; ++mi)
#pragma unroll
      for (int ni = 0; ni < 6; ++ni)
        acc[mi][ni] = __builtin_amdgcn_mfma_f32_16x16x32_bf16(af[mi], bfv[ni], acc[mi][ni], 0, 0, 0);
  }

  const int bctx = rowBase / 384;
#pragma unroll
  for (int mi = 0; mi < 4; ++mi) {
#pragma unroll
    for (int ni = 0; ni < 6; ++ni) {
      const int col = wc4 * 96 + ni * 16 + l16;
      const bool act = (wc4 * 96 + ni * 16) < 256;  // wave/fragment-uniform
      const float bv = bias[col];
      const float cv = act ? cvec[bctx * 256 + col] : 0.f;
      const int row0 = rowBase + wr * 64 + mi * 16 + quad * 4;
#pragma unroll
      for (int r = 0; r < 4; ++r) {
        float v = acc[mi][ni][r] + bv + cv;
        if (act) v = v > 0.f ? v : __expf(v) - 1.f;
        C[(size_t)(row0 + r) * 384 + col] = (bf16)v;
      }
    }
  }
}

// ---------------- prep: weight transposes / pads / plain casts (f32 -> bf16), one launch ----------------
__global__ void prep_kernel(
    const float* fgW1, const float* fgWs, const float* fgW2, const float* fgWg,
    const float* fgb1, const float* fgbs,
    const float* svW1, const float* svWg, const float* svW2,
    const float* enW1, const float* enWg, const float* enW2,
    const float* Wq, const float* Wk, const float* Wv, const float* Wo,
    bf16* fgW1WsT, bf16* fgWgPT, bf16* fgW2C, float* bias384,
    bf16* svW1T, bf16* svWgT, bf16* svW2C,
    bf16* enW1T, bf16* enWgT, bf16* enW2C,
    bf16* WqkvT, bf16* WoT)
{
  long i = (long)blockIdx.x * 256 + threadIdx.x;
  if (i < 1179648) {               // fused [W1 | Ws(pad12->128)] transposed: 384 x 3072
    int n = i / 3072, k = i % 3072; float v;
    if (n < 256) v = fgW1[(size_t)k * 256 + n];
    else { int nn = n - 256; v = (nn < 12) ? fgWs[(size_t)k * 12 + nn] : 0.f; }
    fgW1WsT[i] = (bf16)v; return; } i -= 1179648;
  if (i < 32768)  { int n = i >> 8, k = i & 255; fgWgPT[i] = (n < 24) ? (bf16)fgWg[k * 24 + n] : (bf16)0.f; return; } i -= 32768;
  if (i < 65536)  { fgW2C[i] = (bf16)fgW2[i]; return; } i -= 65536;
  if (i < 384)    { bias384[i] = (i < 256) ? fgb1[i] : ((i < 268) ? fgbs[i - 256] : 0.f); return; } i -= 384;
  if (i < 786432) { long v = i >> 16, r = i & 65535; int n = r >> 8, k = r & 255; svW1T[i] = (bf16)svW1[(v << 16) + k * 256 + n]; return; } i -= 786432;
  if (i < 1572864){ long v = i >> 17, r = i & 131071; int n = r >> 8, k = r & 255; svWgT[i] = (bf16)svWg[(v << 17) + k * 512 + n]; return; } i -= 1572864;
  if (i < 786432) { svW2C[i] = (bf16)svW2[i]; return; } i -= 786432;
  if (i < 65536)  { int n = i >> 8, k = i & 255; enW1T[i] = (bf16)enW1[k * 256 + n]; return; } i -= 65536;
  if (i < 131072) { int n = i >> 8, k = i & 255; enWgT[i] = (bf16)enWg[k * 512 + n]; return; } i -= 131072;
  if (i < 65536)  { enW2C[i] = (bf16)enW2[i]; return; } i -= 65536;
  if (i < 163840) { int n = i >> 8, k = i & 255; float val;
                    if (n < 256)      val = Wq[(n >> 6) * 16384 + k * 64 + (n & 63)];
                    else if (n < 512) { int nn = n - 256; val = Wk[(nn >> 6) * 16384 + k * 64 + (nn & 63)]; }
                    else if (n < 576) val = Wv[k * 64 + (n - 512)];
                    else              val = 0.f;
                    WqkvT[i] = (bf16)val; return; } i -= 163840;
  if (i < 16384)  { int n = i >> 6, k = i & 63; WoT[i] = (bf16)Wo[k * 256 + n]; }
}

// ---------------- fused bias: bF = b2@Wg + bg (f32 exact); sv/en stored PERMUTED ----------------
__global__ void biasfuse_kernel(const float* fgb2, const float* fgWg, const float* fgbg,
                                const float* svb2, const float* svWg, const float* svbg,
                                const float* enb2, const float* enWg, const float* enbg,
                                float* fgBF, float* svBFP, float* enBFP)
{
  int i = blockIdx.x * 256 + threadIdx.x;
  if (i < 128) {
    float s = 0.f;
    if (i < 24) { s = fgbg[i]; for (int k = 0; k < 256; ++k) s += fgb2[k] * fgWg[k * 24 + i]; }
    fgBF[i] = s; return; } i -= 128;
  if (i < 6144) {
    int v = i >> 9, n = i & 511;
    float s = svbg[v * 512 + n];
    const float* W = svWg + (size_t)v * 131072;
    const float* b2 = svb2 + v * 256;
    for (int k = 0; k < 256; ++k) s += b2[k] * W[k * 512 + n];
    svBFP[v * 512 + perm512(n)] = s; return; } i -= 6144;
  if (i < 512) {
    float s = enbg[i];
    for (int k = 0; k < 256; ++k) s += enb2[k] * enWg[k * 512 + i];
    enBFP[perm512(i)] = s; }
}

// ---------------- cvec[b][n] = context[b] @ Wc  (fg / en), all f32 ----------------
__global__ void cvec_kernel(const float* __restrict__ ctx, const float* __restrict__ WcFg,
                            const float* __restrict__ WcEn, float* __restrict__ outFg,
                            float* __restrict__ outEn) {
  int b = blockIdx.x, n = threadIdx.x;
  const float* Wc = blockIdx.y ? WcEn : WcFg;
  float* o = blockIdx.y ? outEn : outFg;
  float acc = 0.f;
  for (int d = 0; d < 256; ++d) acc += ctx[b * 256 + d] * Wc[d * 256 + n];
  o[b * 256 + n] = acc;
}

// ---------------- lnsm12: gate + w = softmax(LN(skip + gated)) over V=12 ----------------
__global__ void lnsm12_kernel(const bf16* __restrict__ B384, const bf16* __restrict__ GP,
                              const float* __restrict__ lng, const float* __restrict__ lnb,
                              float* __restrict__ w) {
  int r = blockIdx.x * 256 + threadIdx.x;
  if (r >= BTR) return;
  float y[12]; float m = 0.f;
#pragma unroll
  for (int j = 0; j < 12; ++j) {
    float a = (float)GP[(size_t)r * 128 + j];
    float g = (float)GP[(size_t)r * 128 + 12 + j];
    float gated = a / (1.f + __expf(-g));
    y[j] = (float)B384[(size_t)r * 384 + 256 + j] + gated; m += y[j];
  }
  m *= (1.f / 12.f);
  float var = 0.f;
#pragma unroll
  for (int j = 0; j < 12; ++j) { float d = y[j] - m; var += d * d; }
  var *= (1.f / 12.f);
  float rstd = rsqrtf(var + 1e-5f);
  float mx = -1e30f;
#pragma unroll
  for (int j = 0; j < 12; ++j) { y[j] = (y[j] - m) * rstd * lng[j] + lnb[j]; mx = fmaxf(mx, y[j]); }
  float s = 0.f;
#pragma unroll
  for (int j = 0; j < 12; ++j) { y[j] = __expf(y[j] - mx); s += y[j]; }
  float inv = 1.f / s;
#pragma unroll
  for (int j = 0; j < 12; ++j) w[r * 12 + j] = y[j] * inv;
}

// ---------------- block (256-thr) reduce of two sums ----------------
__device__ __forceinline__ void block_sum2(float a, float b, float& oa, float& ob) {
#pragma unroll
  for (int o = 32; o; o >>= 1) { a += __shfl_xor(a, o); b += __shfl_xor(b, o); }
  __shared__ float ra[4], rb[4];
  int w = threadIdx.x >> 6;
  if ((threadIdx.x & 63) == 0) { ra[w] = a; rb[w] = b; }
  __syncthreads();
  oa = ra[0] + ra[1] + ra[2] + ra[3];
  ob = rb[0] + rb[1] + rb[2] + rb[3];
  __syncthreads();
}

// ---------------- per-variable GRN tail for 4 vars: LN + weighted acc (gated precomputed) ----------------
__global__ __launch_bounds__(256)
void selacc4_kernel(const bf16* __restrict__ GATED, const float* __restrict__ x,
                    const float* __restrict__ w, const float* __restrict__ lng,
                    const float* __restrict__ lnb, float* __restrict__ sel,
                    bf16* __restrict__ selb, int v0, int isFirst, int isLast) {
  int r = blockIdx.x, d = threadIdx.x;
  float acc = isFirst ? 0.f : sel[(size_t)r * 256 + d];
#pragma unroll
  for (int vv = 0; vv < 4; ++vv) {
    int v = v0 + vv;
    float gated = (float)GATED[(size_t)vv * ((size_t)BTR * 256) + (size_t)r * 256 + d];
    float y = x[(size_t)r * 3072 + v * 256 + d] + gated;
    float s1, s2;
    block_sum2(y, y * y, s1, s2);
    float mean = s1 * (1.f / 256.f);
    float var  = s2 * (1.f / 256.f) - mean * mean;
    float val  = (y - mean) * rsqrtf(var + 1e-5f) * lng[v * 256 + d] + lnb[v * 256 + d];
    acc += w[r * 12 + v] * val;
  }
  if (isLast) selb[(size_t)r * 256 + d] = (bf16)acc;
  else        sel[(size_t)r * 256 + d] = acc;
}

// ---------------- enrichment GRN tail: LN(skip + gated) -> enr (gated precomputed) ----------------
__global__ __launch_bounds__(256)
void enrln_kernel(const bf16* __restrict__ GATED, const bf16* __restrict__ skip,
                  const float* __restrict__ lng, const float* __restrict__ lnb,
                  bf16* __restrict__ out) {
  int r = blockIdx.x, d = threadIdx.x;
  float gated = (float)GATED[(size_t)r * 256 + d];
  float y = (float)skip[(size_t)r * 256 + d] + gated;
  float s1, s2;
  block_sum2(y, y * y, s1, s2);
  float mean = s1 * (1.f / 256.f);
  float var = s2 * (1.f / 256.f) - mean * mean;
  float norm = (y - mean) * rsqrtf(var + 1e-5f);
  out[(size_t)r * 256 + d] = (bf16)(norm * lng[d] + lnb[d]);
}

// ---------------- Pbar[b,q,:] = (1/4) sum_h softmax(S[h,b,q,:]) ----------------
__global__ __launch_bounds__(384)
void softmax_avg_kernel(const bf16* __restrict__ S, bf16* __restrict__ P) {
  const int bq = blockIdx.x;
  const int b = bq / 384, q = bq % 384;
  const int j = threadIdx.x;
  const int w = j >> 6;
  __shared__ float red[6];
  float pb = 0.f;
  for (int h = 0; h < 4; ++h) {
    float s = (float)S[((size_t)((h * 64 + b) * 384 + q)) * 384 + j];
    float m = s;
#pragma unroll
    for (int o = 32; o; o >>= 1) m = fmaxf(m, __shfl_xor(m, o));
    if ((j & 63) == 0) red[w] = m;
    __syncthreads();
    m = fmaxf(fmaxf(fmaxf(red[0], red[1]), fmaxf(red[2], red[3])), fmaxf(red[4], red[5]));
    __syncthreads();
    float e = __expf(s - m);
    float l = e;
#pragma unroll
    for (int o = 32; o; o >>= 1) l += __shfl_xor(l, o);
    if ((j & 63) == 0) red[w] = l;
    __syncthreads();
    l = red[0] + red[1] + red[2] + red[3] + red[4] + red[5];
    __syncthreads();
    pb += e / l;
  }
  P[(size_t)bq * 384 + j] = (bf16)(0.25f * pb);
}

// ---------------- UT[b][d][t] = U[b*384+t][d] ----------------
__global__ void transpose_u_kernel(const bf16* __restrict__ U, bf16* __restrict__ UT) {
  int t = blockIdx.x, b = blockIdx.y, d = threadIdx.x;
  UT[((size_t)b * 256 + d) * 384 + t] = U[((size_t)b * 384 + t) * 256 + d];
}

// ================= host side =================
template<int EPI, bool AF32, bool CF32>
static inline void rungemm(hipStream_t s,
    const void* A, int lda, const bf16* Bt, int ldb, void* C, int ldc,
    int M, int N, int K,
    const float* bias = nullptr, const float* cvec = nullptr,
    int Z = 1, int zdiv = 1,
    long sAh = 0, long sAb = 0, long sBh = 0, long sBb = 0, long sC = 0, long sBias = 0)
{
  dim3 grid(N / 128, M / 128, Z);
  gemm_kernel<EPI, AF32, CF32><<<grid, 256, 0, s>>>(A, lda, sAh, sAb, Bt, ldb, sBh, sBb, C, ldc, sC, K, zdiv, bias, cvec, sBias);
}

extern "C" void kernel_launch(void* const* d_in, const int* in_sizes, int n_in,
                              void* d_out, int out_size, void* d_ws, size_t ws_size,
                              hipStream_t stream)
{
  (void)in_sizes; (void)n_in; (void)out_size;
  const float* x      = (const float*)d_in[0];
  const float* ctx    = (const float*)d_in[1];
  const float* fg_W1  = (const float*)d_in[2];
  const float* fg_b1  = (const float*)d_in[3];
  const float* fg_Wc  = (const float*)d_in[4];
  const float* fg_W2  = (const float*)d_in[5];
  const float* fg_b2  = (const float*)d_in[6];
  const float* fg_Wg  = (const float*)d_in[7];
  const float* fg_bg  = (const float*)d_in[8];
  const float* fg_Ws  = (const float*)d_in[9];
  const float* fg_bs  = (const float*)d_in[10];
  const float* fg_lng = (const float*)d_in[11];
  const float* fg_lnb = (const float*)d_in[12];
  const float* sv_W1  = (const float*)d_in[13];
  const float* sv_b1  = (const float*)d_in[14];
  const float* sv_W2  = (const float*)d_in[15];
  const float* sv_b2  = (const float*)d_in[16];
  const float* sv_Wg  = (const float*)d_in[17];
  const float* sv_bg  = (const float*)d_in[18];
  const float* sv_lng = (const float*)d_in[19];
  const float* sv_lnb = (const float*)d_in[20];
  const float* en_W1  = (const float*)d_in[21];
  const float* en_b1  = (const float*)d_in[22];
  const float* en_Wc  = (const float*)d_in[23];
  const float* en_W2  = (const float*)d_in[24];
  const float* en_b2  = (const float*)d_in[25];
  const float* en_Wg  = (const float*)d_in[26];
  const float* en_bg  = (const float*)d_in[27];
  const float* en_lng = (const float*)d_in[28];
  const float* en_lnb = (const float*)d_in[29];
  const float* Wq     = (const float*)d_in[30];
  const float* Wk     = (const float*)d_in[31];
  const float* Wv     = (const float*)d_in[32];
  const float* Wo     = (const float*)d_in[33];

  // -------- workspace layout (bytes) --------
  static constexpr size_t OFF_FGW1WST = 0;                          // 384x3072 bf16
  static constexpr size_t OFF_FGWGPT  = OFF_FGW1WST + 2359296;      // 128x256 bf16
  static constexpr size_t OFF_FGW2C   = OFF_FGWGPT  + 65536;        // 256x256 bf16
  static constexpr size_t OFF_FGW2GT  = OFF_FGW2C   + 131072;       // 128x256 bf16
  static constexpr size_t OFF_BIAS384 = OFF_FGW2GT  + 65536;        // 384 f32
  static constexpr size_t OFF_FGBF    = OFF_BIAS384 + 1536;         // 128 f32
  static constexpr size_t OFF_SVW1T   = OFF_FGBF    + 512;          // 12x256x256 bf16
  static constexpr size_t OFF_SVWGT   = OFF_SVW1T   + 1572864;      // 12x512x256 bf16
  static constexpr size_t OFF_SVW2C   = OFF_SVWGT   + 3145728;      // 12x256x256 bf16
  static constexpr size_t OFF_SVW2GPT = OFF_SVW2C   + 1572864;      // 12x512x256 bf16 (row-permuted)
  static constexpr size_t OFF_SVBFP   = OFF_SVW2GPT + 3145728;      // 12x512 f32 (permuted)
  static constexpr size_t OFF_ENW1T   = OFF_SVBFP   + 24576;        // 256x256 bf16
  static constexpr size_t OFF_ENWGT   = OFF_ENW1T   + 131072;       // 512x256 bf16
  static constexpr size_t OFF_ENW2C   = OFF_ENWGT   + 262144;       // 256x256 bf16
  static constexpr size_t OFF_ENW2GPT = OFF_ENW2C   + 131072;       // 512x256 bf16 (row-permuted)
  static constexpr size_t OFF_ENBFP   = OFF_ENW2GPT + 262144;       // 512 f32 (permuted)
  static constexpr size_t OFF_WQKVT   = OFF_ENBFP   + 2048;         // 640x256 bf16
  static constexpr size_t OFF_WOT     = OFF_WQKVT   + 327680;       // 256x64 bf16
  static constexpr size_t OFF_CVECFG  = OFF_WOT     + 32768;        // 64x256 f32
  static constexpr size_t OFF_CVECEN  = OFF_CVECFG  + 65536;
  static constexpr size_t ARENA       = OFF_CVECEN  + 65536;        // = 13,365,248
  // arena overlays (offsets relative to ARENA):
  //  sv : sel@0(25.2M) selb@25165824(12.6M) wbuf@37748736(1.2M) H1G@38928384(50.3M) GATED@89260032(50.3M)
  //  fg : BUF384@38928384(18.9M) GPAD@57802752(6.3M) wbuf@37748736
  //  en : H1EN@38928384 GATEDEN@89260032 selb enr@139591680(12.6M)
  //  att: QKV@0(31.5M) Pbar@38928384(18.9M) Sbuf@64094208(75.5M) U@139591680 UT@64094208
  static constexpr size_t WS_NEEDED = ARENA + 152174592;            // ~158 MB

  if (ws_size < WS_NEEDED) return;  // fail cleanly

  char* ws = (char*)d_ws;
  bf16*  fgW1WsT = (bf16*)(ws + OFF_FGW1WST);
  bf16*  fgWgPT  = (bf16*)(ws + OFF_FGWGPT);
  bf16*  fgW2C   = (bf16*)(ws + OFF_FGW2C);
  bf16*  fgW2gT  = (bf16*)(ws + OFF_FGW2GT);
  float* bias384 = (float*)(ws + OFF_BIAS384);
  float* fgBF    = (float*)(ws + OFF_FGBF);
  bf16*  svW1T   = (bf16*)(ws + OFF_SVW1T);
  bf16*  svWgT   = (bf16*)(ws + OFF_SVWGT);
  bf16*  svW2C   = (bf16*)(ws + OFF_SVW2C);
  bf16*  svW2gPT = (bf16*)(ws + OFF_SVW2GPT);
  float* svBFP   = (float*)(ws + OFF_SVBFP);
  bf16*  enW1T   = (bf16*)(ws + OFF_ENW1T);
  bf16*  enWgT   = (bf16*)(ws + OFF_ENWGT);
  bf16*  enW2C   = (bf16*)(ws + OFF_ENW2C);
  bf16*  enW2gPT = (bf16*)(ws + OFF_ENW2GPT);
  float* enBFP   = (float*)(ws + OFF_ENBFP);
  bf16*  WqkvT   = (bf16*)(ws + OFF_WQKVT);
  bf16*  WoT     = (bf16*)(ws + OFF_WOT);
  float* cvecFg  = (float*)(ws + OFF_CVECFG);
  float* cvecEn  = (float*)(ws + OFF_CVECEN);
  char*  ar      = ws + ARENA;
  float* sel     = (float*)(ar + 0);
  bf16*  selb    = (bf16*)(ar + 25165824);
  float* wbuf    = (float*)(ar + 37748736);
  bf16*  H1G     = (bf16*)(ar + 38928384);
  bf16*  BUF384  = (bf16*)(ar + 38928384);
  bf16*  GPAD    = (bf16*)(ar + 57802752);
  bf16*  H1EN    = (bf16*)(ar + 38928384);
  bf16*  GATED   = (bf16*)(ar + 89260032);
  bf16*  GATEDEN = (bf16*)(ar + 89260032);
  bf16*  enr     = (bf16*)(ar + 139591680);
  bf16*  QKV     = (bf16*)(ar + 0);
  bf16*  Pbar    = (bf16*)(ar + 38928384);
  bf16*  Sbuf    = (bf16*)(ar + 64094208);
  bf16*  U       = (bf16*)(ar + 139591680);
  bf16*  UT      = (bf16*)(ar + 64094208);
  float* out     = (float*)d_out;

  // 1) weight prep
  prep_kernel<<<19010, 256, 0, stream>>>(fg_W1, fg_Ws, fg_W2, fg_Wg, fg_b1, fg_bs,
                                         sv_W1, sv_Wg, sv_W2, en_W1, en_Wg, en_W2,
                                         Wq, Wk, Wv, Wo,
                                         fgW1WsT, fgWgPT, fgW2C, bias384,
                                         svW1T, svWgT, svW2C, enW1T, enWgT, enW2C,
                                         WqkvT, WoT);
  // 2) fused biases (sv/en permuted) + context vectors
  biasfuse_kernel<<<27, 256, 0, stream>>>(fg_b2, fg_Wg, fg_bg, sv_b2, sv_Wg, sv_bg,
                                          en_b2, en_Wg, en_bg, fgBF, svBFP, enBFP);
  cvec_kernel<<<dim3(64, 2), 256, 0, stream>>>(ctx, fg_Wc, en_Wc, cvecFg, cvecEn);

  // 3) combined weights W2g[n][k2] = sum_k Wg[k][n]*W2[k2][k]; sv/en rows stored permuted
  rungemm<0,        false, false>(stream, fgWgPT, 256, fgW2C, 256, fgW2gT, 256, 128, 256, 256);
  rungemm<EPI_PERM, false, false>(stream, svWgT, 256, svW2C, 256, svW2gPT, 256, 512, 256, 256,
                                  nullptr, nullptr, 12, 12, 0, 131072, 0, 65536, 131072);
  rungemm<EPI_PERM, false, false>(stream, enWgT, 256, enW2C, 256, enW2gPT, 256, 512, 256, 256);

  // 4) flattened GRN: wide-tile fused [h1 | skip] GEMM (A-stripe read once), g GEMM, LN+softmax
  fgwide_kernel<<<192, 512, 0, stream>>>(x, fgW1WsT, BUF384, bias384, cvecFg);
  rungemm<EPI_BIAS, false, false>(stream, BUF384, 384, fgW2gT, 256, GPAD, 128, BTR, 128, 256, fgBF);
  lnsm12_kernel<<<96, 256, 0, stream>>>(BUF384, GPAD, fg_lng, fg_lnb, wbuf);

  // 5) per-variable GRNs, batched Z=4 (3 groups), gate fused in W2g epilogue
  for (int g = 0; g < 3; ++g) {
    rungemm<EPI_BIAS|EPI_ELU, true, false>(
        stream, x + g * 4 * 256, 3072, svW1T + (size_t)g * 4 * 65536, 256, H1G, 256, BTR, 256, 256,
        sv_b1 + g * 4 * 256, nullptr, 4, 4, 0, 256, 0, 65536, (long)BTR * 256, 256);
    rungemm<EPI_BIAS|EPI_GATE, false, false>(
        stream, H1G, 256, svW2gPT + (size_t)g * 4 * 131072, 256, GATED, 256, BTR, 512, 256,
        svBFP + g * 4 * 512, nullptr, 4, 4, 0, (long)BTR * 256, 0, 131072, (long)BTR * 256, 512);
    selacc4_kernel<<<BTR, 256, 0, stream>>>(GATED, x, wbuf, sv_lng, sv_lnb, sel, selb,
                                            g * 4, g == 0, g == 2);
  }

  // 6) enrichment GRN (gate fused)
  rungemm<EPI_BIAS|EPI_CVEC|EPI_ELU, false, false>(stream, selb, 256, enW1T, 256, H1EN, 256, BTR, 256, 256, en_b1, cvecEn);
  rungemm<EPI_BIAS|EPI_GATE, false, false>(stream, H1EN, 256, enW2gPT, 256, GATEDEN, 256, BTR, 512, 256, enBFP);
  enrln_kernel<<<BTR, 256, 0, stream>>>(GATEDEN, selb, en_lng, en_lnb, enr);

  // 7) attention
  rungemm<0, false, false>(stream, enr, 256, WqkvT, 256, QKV, 640, BTR, 640, 256);
  rungemm<EPI_ATTN, false, false>(stream, QKV, 640, QKV + 256, 640, Sbuf, 384, 384, 384, 64,
                                  nullptr, nullptr, 256, 64, 64, 245760L, 64, 245760L, 147456L);
  softmax_avg_kernel<<<BTR, 384, 0, stream>>>(Sbuf, Pbar);
  rungemm<0, false, false>(stream, QKV + 512, 640, WoT, 64, U, 256, BTR, 256, 64);
  transpose_u_kernel<<<dim3(384, 64), 256, 0, stream>>>(U, UT);
  rungemm<0, false, true>(stream, Pbar, 384, UT, 384, out, 256, 384, 256, 384,
                          nullptr, nullptr, 64, 1, 147456L, 0, 98304L, 0, 98304L);
}

// Round 3
// 1356.811 us; speedup vs baseline: 1.3797x; 1.0448x over previous
//
#include <hip/hip_runtime.h>
#include <hip/hip_bf16.h>
#include <stdint.h>
#include <stddef.h>

// TFT block on MI355X. B=64 T=384 V=12 D=256 H=4 DK=64.
// R6: (1) software prefetch (next k-tile loads issued before MFMA) in all GEMMs.
// (2) fgwide -> 64-row blocks (grid 384: full CU coverage).
// (3) UT computed directly as GEMM (A=WoT); transpose_u + U eliminated.
typedef __bf16 bf16;
typedef __bf16 bf16x8 __attribute__((ext_vector_type(8)));
typedef float  f32x4  __attribute__((ext_vector_type(4)));

#define BTR 24576   // B*T rows
#define EPI_BIAS  1
#define EPI_CVEC  2
#define EPI_ELU   4
#define EPI_ATTN  8
#define EPI_GATE  32   // N=512 permuted pairs -> C = a*sigmoid(g), width N/2
#define EPI_PERM  64   // C-row permutation for building gate-paired weights

// col permutation: a_j -> 32*(j>>4)+(j&15), g_j -> same +16
__device__ __forceinline__ int perm512(int n) {
  return (n < 256) ? (((n >> 4) << 5) + (n & 15))
                   : ((((n - 256) >> 4) << 5) + ((n - 256) & 15) + 16);
}

// ---------------- 128x128 tile bf16 MFMA GEMM, C[m][n] = sum_k A[m][k]*Bt[n][k] ----------------
template<int EPI, bool AF32, bool CF32>
__global__ __launch_bounds__(256, 2)
void gemm_kernel(const void* __restrict__ Av, int lda, long sAh, long sAb,
                 const bf16* __restrict__ Bt, int ldb, long sBh, long sBb,
                 void* __restrict__ Cv, int ldc, long sC,
                 int K, int zdiv,
                 const float* __restrict__ bias, const float* __restrict__ cvec,
                 long sBias)
{
  __shared__ __align__(16) bf16 As[128 * 32];
  __shared__ __align__(16) bf16 Bs[128 * 32];

  const int tid  = threadIdx.x;
  const int wave = tid >> 6, lane = tid & 63;
  const int wr = wave >> 1, wc = wave & 1;         // 2x2 waves, 64x64 each
  const int quad = lane >> 4, l16 = lane & 15;

  const int z  = blockIdx.z;
  const int hh = z / zdiv, bb = z % zdiv;
  const float* AbF = nullptr; const bf16* AbH = nullptr;
  if constexpr (AF32) AbF = (const float*)Av + (long)hh * sAh + (long)bb * sAb;
  else                AbH = (const bf16*)Av  + (long)hh * sAh + (long)bb * sAb;
  const bf16* Bb = Bt + (long)hh * sBh + (long)bb * sBb;
  float* CbF = nullptr; bf16* CbH = nullptr;
  if constexpr (CF32) CbF = (float*)Cv + (long)z * sC;
  else                CbH = (bf16*)Cv  + (long)z * sC;

  const int rowBase = blockIdx.y * 128;
  const int colBase = blockIdx.x * 128;

  f32x4 acc[4][4];
#pragma unroll
  for (int i = 0; i < 4; ++i)
#pragma unroll
    for (int j = 0; j < 4; ++j) { acc[i][j][0]=0.f; acc[i][j][1]=0.f; acc[i][j][2]=0.f; acc[i][j][3]=0.f; }

  const int r0 = tid >> 2, kc = tid & 3;           // bf16-A / B decode
  const int r1 = tid >> 1, kh = (tid & 1) * 16;    // f32-A decode
  const int arow = (wr * 64 + l16) * 32 + quad * 8;
  const int brow = (wc * 64 + l16) * 32 + quad * 8;

  // -------- prefetch registers (1-deep pipeline) --------
  f32x4 pf0, pf1, pf2, pf3;
  bf16x8 pa0, pa1, pb0, pb1;
  if constexpr (AF32) {
    const float* p = AbF + (size_t)(rowBase + r1) * lda + kh;
    pf0 = *(const f32x4*)(p);     pf1 = *(const f32x4*)(p + 4);
    pf2 = *(const f32x4*)(p + 8); pf3 = *(const f32x4*)(p + 12);
  } else {
    pa0 = *(const bf16x8*)(AbH + (size_t)(rowBase + r0)      * lda + kc * 8);
    pa1 = *(const bf16x8*)(AbH + (size_t)(rowBase + 64 + r0) * lda + kc * 8);
  }
  pb0 = *(const bf16x8*)(Bb + (size_t)(colBase + r0)      * ldb + kc * 8);
  pb1 = *(const bf16x8*)(Bb + (size_t)(colBase + 64 + r0) * ldb + kc * 8);

  for (int k0 = 0; k0 < K; k0 += 32) {
    __syncthreads();   // previous iteration's ds_reads complete before overwrite
    if constexpr (AF32) {
      bf16x8 a0, a1;
#pragma unroll
      for (int e = 0; e < 4; ++e) {
        a0[e] = (bf16)pf0[e]; a0[4 + e] = (bf16)pf1[e];
        a1[e] = (bf16)pf2[e]; a1[4 + e] = (bf16)pf3[e];
      }
      *(bf16x8*)(As + r1 * 32 + kh)     = a0;
      *(bf16x8*)(As + r1 * 32 + kh + 8) = a1;
    } else {
      *(bf16x8*)(As +        r0 * 32 + kc * 8) = pa0;
      *(bf16x8*)(As + 2048 + r0 * 32 + kc * 8) = pa1;
    }
    *(bf16x8*)(Bs +        r0 * 32 + kc * 8) = pb0;
    *(bf16x8*)(Bs + 2048 + r0 * 32 + kc * 8) = pb1;
    __syncthreads();

    // issue next-tile loads BEFORE the MFMA cluster: they stay in flight
    // across the barrier and drain at the next LDS-write (T3 minimum).
    const int k1 = k0 + 32;
    if (k1 < K) {
      if constexpr (AF32) {
        const float* p = AbF + (size_t)(rowBase + r1) * lda + k1 + kh;
        pf0 = *(const f32x4*)(p);     pf1 = *(const f32x4*)(p + 4);
        pf2 = *(const f32x4*)(p + 8); pf3 = *(const f32x4*)(p + 12);
      } else {
        pa0 = *(const bf16x8*)(AbH + (size_t)(rowBase + r0)      * lda + k1 + kc * 8);
        pa1 = *(const bf16x8*)(AbH + (size_t)(rowBase + 64 + r0) * lda + k1 + kc * 8);
      }
      pb0 = *(const bf16x8*)(Bb + (size_t)(colBase + r0)      * ldb + k1 + kc * 8);
      pb1 = *(const bf16x8*)(Bb + (size_t)(colBase + 64 + r0) * ldb + k1 + kc * 8);
    }

    bf16x8 af[4], bfv[4];
#pragma unroll
    for (int mi = 0; mi < 4; ++mi) af[mi]  = *(const bf16x8*)(As + arow + mi * 512);
#pragma unroll
    for (int ni = 0; ni < 4; ++ni) bfv[ni] = *(const bf16x8*)(Bs + brow + ni * 512);
#pragma unroll
    for (int mi = 0; mi < 4; ++mi)
#pragma unroll
      for (int ni = 0; ni < 4; ++ni)
        acc[mi][ni] = __builtin_amdgcn_mfma_f32_16x16x32_bf16(af[mi], bfv[ni], acc[mi][ni], 0, 0, 0);
  }

  // epilogue. C/D layout: col = lane&15, row = quad*4 + reg  [m89-verified]
  if constexpr (EPI & EPI_GATE) {
    const float* bp = bias + (size_t)z * sBias;
#pragma unroll
    for (int mi = 0; mi < 4; ++mi) {
#pragma unroll
      for (int nj = 0; nj < 2; ++nj) {
        const int ni = nj * 2;
        const int pa = colBase + wc * 64 + ni * 16 + l16;
        const int j  = (colBase >> 1) + wc * 32 + nj * 16 + l16;
        const float ba = bp[pa], bg = bp[pa + 16];
        const int row0 = rowBase + wr * 64 + mi * 16 + quad * 4;
#pragma unroll
        for (int r = 0; r < 4; ++r) {
          float a = acc[mi][ni][r]     + ba;
          float g = acc[mi][ni + 1][r] + bg;
          CbH[(size_t)(row0 + r) * ldc + j] = (bf16)(a / (1.f + __expf(-g)));
        }
      }
    }
    return;
  }
  const int bctx = (EPI & EPI_CVEC) ? (rowBase / 384) : 0;
  const float* bp = (EPI & EPI_BIAS) ? bias + (size_t)z * sBias : nullptr;
#pragma unroll
  for (int mi = 0; mi < 4; ++mi) {
#pragma unroll
    for (int ni = 0; ni < 4; ++ni) {
      const int row0 = rowBase + wr * 64 + mi * 16 + quad * 4;
      const int col  = colBase + wc * 64 + ni * 16 + l16;
      float bv = (EPI & EPI_BIAS) ? bp[col] : 0.f;
      float cv = (EPI & EPI_CVEC) ? cvec[bctx * 256 + col] : 0.f;
#pragma unroll
      for (int r = 0; r < 4; ++r) {
        float v = acc[mi][ni][r] + bv + cv;
        if (EPI & EPI_ELU)  v = v > 0.f ? v : __expf(v) - 1.f;
        if (EPI & EPI_ATTN) { v *= 0.125f; if (col > row0 + r) v = -1e9f; }
        int srow = row0 + r;
        if constexpr (EPI & EPI_PERM) srow = perm512(srow);
        if constexpr (CF32) CbF[(size_t)srow * ldc + col] = v;
        else                CbH[(size_t)srow * ldc + col] = (bf16)v;
      }
    }
  }
}

// ---------------- fg wide kernel: 64 rows x ALL 384 cols per block, K=3072 ----------------
// grid = 384 (full CU coverage). A (x, f32) stripe read exactly once from HBM.
// B = fgW1WsT (384x3072 bf16, L2-resident). 1-deep prefetch pipeline.
__global__ __launch_bounds__(256, 2)
void fgwide_kernel(const float* __restrict__ A, const bf16* __restrict__ Bt,
                   bf16* __restrict__ C, const float* __restrict__ bias,
                   const float* __restrict__ cvec)
{
  __shared__ __align__(16) bf16 As[64 * 32];
  __shared__ __align__(16) bf16 Bs[384 * 32];
  const int tid = threadIdx.x;
  const int wave = tid >> 6, lane = tid & 63;     // wave = column group (96 cols)
  const int quad = lane >> 4, l16 = lane & 15;
  const int rowBase = blockIdx.x * 64;

  f32x4 acc[4][6];
#pragma unroll
  for (int i = 0; i < 4; ++i)
#pragma unroll
    for (int j = 0; j < 6; ++j) { acc[i][j][0]=0.f; acc[i][j][1]=0.f; acc[i][j][2]=0.f; acc[i][j][3]=0.f; }

  const int r1 = tid >> 2, kh = (tid & 3) * 8;    // A staging: 8 f32/thread, rows 0..63
  const int arow = l16 * 32 + quad * 8;
  const int brow = (wave * 96 + l16) * 32 + quad * 8;

  f32x4 pf0, pf1;
  bf16x8 pbv[6];
  {
    const float* p = A + (size_t)(rowBase + r1) * 3072 + kh;
    pf0 = *(const f32x4*)(p); pf1 = *(const f32x4*)(p + 4);
#pragma unroll
    for (int c = 0; c < 6; ++c) {
      const int idx = c * 256 + tid, rb = idx >> 2, kc2 = idx & 3;
      pbv[c] = *(const bf16x8*)(Bt + (size_t)rb * 3072 + kc2 * 8);
    }
  }
  for (int k0 = 0; k0 < 3072; k0 += 32) {
    __syncthreads();
    bf16x8 av;
#pragma unroll
    for (int e = 0; e < 4; ++e) { av[e] = (bf16)pf0[e]; av[4 + e] = (bf16)pf1[e]; }
    *(bf16x8*)(As + r1 * 32 + kh) = av;
#pragma unroll
    for (int c = 0; c < 6; ++c) {
      const int idx = c * 256 + tid, rb = idx >> 2, kc2 = idx & 3;
      *(bf16x8*)(Bs + rb * 32 + kc2 * 8) = pbv[c];
    }
    __syncthreads();

    const int k1 = k0 + 32;
    if (k1 < 3072) {
      const float* p = A + (size_t)(rowBase + r1) * 3072 + k1 + kh;
      pf0 = *(const f32x4*)(p); pf1 = *(const f32x4*)(p + 4);
#pragma unroll
      for (int c = 0; c < 6; ++c) {
        const int idx = c * 256 + tid, rb = idx >> 2, kc2 = idx & 3;
        pbv[c] = *(const bf16x8*)(Bt + (size_t)rb * 3072 + k1 + kc2 * 8);
      }
    }

    bf16x8 af[4], bfv[6];
#pragma unroll
    for (int mi = 0; mi < 4; ++mi) af[mi]  = *(const bf16x8*)(As + arow + mi * 512);
#pragma unroll
    for (int ni = 0; ni < 6; ++ni) bfv[ni] = *(const bf16x8*)(Bs + brow + ni * 512);
#pragma unroll
    for (int mi = 0; mi < 4; ++mi)
#pragma unroll
      for (int ni = 0; ni < 6; ++ni)
        acc[mi][ni] = __builtin_amdgcn_mfma_f32_16x16x32_bf16(af[mi], bfv[ni], acc[mi][ni], 0, 0, 0);
  }

  const int bctx = rowBase / 384;   // 64-row tile never crosses a b boundary
#pragma unroll
  for (int mi = 0; mi < 4; ++mi) {
#pragma unroll
    for (int ni = 0; ni < 6; ++ni) {
      const int col = wave * 96 + ni * 16 + l16;
      const bool act = (wave * 96 + ni * 16) < 256;  // fragment-uniform
      const float bv = bias[col];
      const float cv = act ? cvec[bctx * 256 + col] : 0.f;
      const int row0 = rowBase + mi * 16 + quad * 4;
#pragma unroll
      for (int r = 0; r < 4; ++r) {
        float v = acc[mi][ni][r] + bv + cv;
        if (act) v = v > 0.f ? v : __expf(v) - 1.f;
        C[(size_t)(row0 + r) * 384 + col] = (bf16)v;
      }
    }
  }
}

// ---------------- prep: weight transposes / pads / plain casts (f32 -> bf16), one launch ----------------
__global__ void prep_kernel(
    const float* fgW1, const float* fgWs, const float* fgW2, const float* fgWg,
    const float* fgb1, const float* fgbs,
    const float* svW1, const float* svWg, const float* svW2,
    const float* enW1, const float* enWg, const float* enW2,
    const float* Wq, const float* Wk, const float* Wv, const float* Wo,
    bf16* fgW1WsT, bf16* fgWgPT, bf16* fgW2C, float* bias384,
    bf16* svW1T, bf16* svWgT, bf16* svW2C,
    bf16* enW1T, bf16* enWgT, bf16* enW2C,
    bf16* WqkvT, bf16* WoT)
{
  long i = (long)blockIdx.x * 256 + threadIdx.x;
  if (i < 1179648) {               // fused [W1 | Ws(pad12->128)] transposed: 384 x 3072
    int n = i / 3072, k = i % 3072; float v;
    if (n < 256) v = fgW1[(size_t)k * 256 + n];
    else { int nn = n - 256; v = (nn < 12) ? fgWs[(size_t)k * 12 + nn] : 0.f; }
    fgW1WsT[i] = (bf16)v; return; } i -= 1179648;
  if (i < 32768)  { int n = i >> 8, k = i & 255; fgWgPT[i] = (n < 24) ? (bf16)fgWg[k * 24 + n] : (bf16)0.f; return; } i -= 32768;
  if (i < 65536)  { fgW2C[i] = (bf16)fgW2[i]; return; } i -= 65536;
  if (i < 384)    { bias384[i] = (i < 256) ? fgb1[i] : ((i < 268) ? fgbs[i - 256] : 0.f); return; } i -= 384;
  if (i < 786432) { long v = i >> 16, r = i & 65535; int n = r >> 8, k = r & 255; svW1T[i] = (bf16)svW1[(v << 16) + k * 256 + n]; return; } i -= 786432;
  if (i < 1572864){ long v = i >> 17, r = i & 131071; int n = r >> 8, k = r & 255; svWgT[i] = (bf16)svWg[(v << 17) + k * 512 + n]; return; } i -= 1572864;
  if (i < 786432) { svW2C[i] = (bf16)svW2[i]; return; } i -= 786432;
  if (i < 65536)  { int n = i >> 8, k = i & 255; enW1T[i] = (bf16)enW1[k * 256 + n]; return; } i -= 65536;
  if (i < 131072) { int n = i >> 8, k = i & 255; enWgT[i] = (bf16)enWg[k * 512 + n]; return; } i -= 131072;
  if (i < 65536)  { enW2C[i] = (bf16)enW2[i]; return; } i -= 65536;
  if (i < 163840) { int n = i >> 8, k = i & 255; float val;
                    if (n < 256)      val = Wq[(n >> 6) * 16384 + k * 64 + (n & 63)];
                    else if (n < 512) { int nn = n - 256; val = Wk[(nn >> 6) * 16384 + k * 64 + (nn & 63)]; }
                    else if (n < 576) val = Wv[k * 64 + (n - 512)];
                    else              val = 0.f;
                    WqkvT[i] = (bf16)val; return; } i -= 163840;
  if (i < 16384)  { int n = i >> 6, k = i & 63; WoT[i] = (bf16)Wo[k * 256 + n]; }
}

// ---------------- fused bias: bF = b2@Wg + bg (f32 exact); sv/en stored PERMUTED ----------------
__global__ void biasfuse_kernel(const float* fgb2, const float* fgWg, const float* fgbg,
                                const float* svb2, const float* svWg, const float* svbg,
                                const float* enb2, const float* enWg, const float* enbg,
                                float* fgBF, float* svBFP, float* enBFP)
{
  int i = blockIdx.x * 256 + threadIdx.x;
  if (i < 128) {
    float s = 0.f;
    if (i < 24) { s = fgbg[i]; for (int k = 0; k < 256; ++k) s += fgb2[k] * fgWg[k * 24 + i]; }
    fgBF[i] = s; return; } i -= 128;
  if (i < 6144) {
    int v = i >> 9, n = i & 511;
    float s = svbg[v * 512 + n];
    const float* W = svWg + (size_t)v * 131072;
    const float* b2 = svb2 + v * 256;
    for (int k = 0; k < 256; ++k) s += b2[k] * W[k * 512 + n];
    svBFP[v * 512 + perm512(n)] = s; return; } i -= 6144;
  if (i < 512) {
    float s = enbg[i];
    for (int k = 0; k < 256; ++k) s += enb2[k] * enWg[k * 512 + i];
    enBFP[perm512(i)] = s; }
}

// ---------------- cvec[b][n] = context[b] @ Wc  (fg / en), all f32 ----------------
__global__ void cvec_kernel(const float* __restrict__ ctx, const float* __restrict__ WcFg,
                            const float* __restrict__ WcEn, float* __restrict__ outFg,
                            float* __restrict__ outEn) {
  int b = blockIdx.x, n = threadIdx.x;
  const float* Wc = blockIdx.y ? WcEn : WcFg;
  float* o = blockIdx.y ? outEn : outFg;
  float acc = 0.f;
  for (int d = 0; d < 256; ++d) acc += ctx[b * 256 + d] * Wc[d * 256 + n];
  o[b * 256 + n] = acc;
}

// ---------------- lnsm12: gate + w = softmax(LN(skip + gated)) over V=12 ----------------
__global__ void lnsm12_kernel(const bf16* __restrict__ B384, const bf16* __restrict__ GP,
                              const float* __restrict__ lng, const float* __restrict__ lnb,
                              float* __restrict__ w) {
  int r = blockIdx.x * 256 + threadIdx.x;
  if (r >= BTR) return;
  float y[12]; float m = 0.f;
#pragma unroll
  for (int j = 0; j < 12; ++j) {
    float a = (float)GP[(size_t)r * 128 + j];
    float g = (float)GP[(size_t)r * 128 + 12 + j];
    float gated = a / (1.f + __expf(-g));
    y[j] = (float)B384[(size_t)r * 384 + 256 + j] + gated; m += y[j];
  }
  m *= (1.f / 12.f);
  float var = 0.f;
#pragma unroll
  for (int j = 0; j < 12; ++j) { float d = y[j] - m; var += d * d; }
  var *= (1.f / 12.f);
  float rstd = rsqrtf(var + 1e-5f);
  float mx = -1e30f;
#pragma unroll
  for (int j = 0; j < 12; ++j) { y[j] = (y[j] - m) * rstd * lng[j] + lnb[j]; mx = fmaxf(mx, y[j]); }
  float s = 0.f;
#pragma unroll
  for (int j = 0; j < 12; ++j) { y[j] = __expf(y[j] - mx); s += y[j]; }
  float inv = 1.f / s;
#pragma unroll
  for (int j = 0; j < 12; ++j) w[r * 12 + j] = y[j] * inv;
}

// ---------------- block (256-thr) reduce of two sums ----------------
__device__ __forceinline__ void block_sum2(float a, float b, float& oa, float& ob) {
#pragma unroll
  for (int o = 32; o; o >>= 1) { a += __shfl_xor(a, o); b += __shfl_xor(b, o); }
  __shared__ float ra[4], rb[4];
  int w = threadIdx.x >> 6;
  if ((threadIdx.x & 63) == 0) { ra[w] = a; rb[w] = b; }
  __syncthreads();
  oa = ra[0] + ra[1] + ra[2] + ra[3];
  ob = rb[0] + rb[1] + rb[2] + rb[3];
  __syncthreads();
}

// ---------------- per-variable GRN tail for 4 vars: LN + weighted acc (gated precomputed) ----------------
__global__ __launch_bounds__(256)
void selacc4_kernel(const bf16* __restrict__ GATED, const float* __restrict__ x,
                    const float* __restrict__ w, const float* __restrict__ lng,
                    const float* __restrict__ lnb, float* __restrict__ sel,
                    bf16* __restrict__ selb, int v0, int isFirst, int isLast) {
  int r = blockIdx.x, d = threadIdx.x;
  float acc = isFirst ? 0.f : sel[(size_t)r * 256 + d];
#pragma unroll
  for (int vv = 0; vv < 4; ++vv) {
    int v = v0 + vv;
    float gated = (float)GATED[(size_t)vv * ((size_t)BTR * 256) + (size_t)r * 256 + d];
    float y = x[(size_t)r * 3072 + v * 256 + d] + gated;
    float s1, s2;
    block_sum2(y, y * y, s1, s2);
    float mean = s1 * (1.f / 256.f);
    float var  = s2 * (1.f / 256.f) - mean * mean;
    float val  = (y - mean) * rsqrtf(var + 1e-5f) * lng[v * 256 + d] + lnb[v * 256 + d];
    acc += w[r * 12 + v] * val;
  }
  if (isLast) selb[(size_t)r * 256 + d] = (bf16)acc;
  else        sel[(size_t)r * 256 + d] = acc;
}

// ---------------- enrichment GRN tail: LN(skip + gated) -> enr (gated precomputed) ----------------
__global__ __launch_bounds__(256)
void enrln_kernel(const bf16* __restrict__ GATED, const bf16* __restrict__ skip,
                  const float* __restrict__ lng, const float* __restrict__ lnb,
                  bf16* __restrict__ out) {
  int r = blockIdx.x, d = threadIdx.x;
  float gated = (float)GATED[(size_t)r * 256 + d];
  float y = (float)skip[(size_t)r * 256 + d] + gated;
  float s1, s2;
  block_sum2(y, y * y, s1, s2);
  float mean = s1 * (1.f / 256.f);
  float var = s2 * (1.f / 256.f) - mean * mean;
  float norm = (y - mean) * rsqrtf(var + 1e-5f);
  out[(size_t)r * 256 + d] = (bf16)(norm * lng[d] + lnb[d]);
}

// ---------------- Pbar[b,q,:] = (1/4) sum_h softmax(S[h,b,q,:]) ----------------
__global__ __launch_bounds__(384)
void softmax_avg_kernel(const bf16* __restrict__ S, bf16* __restrict__ P) {
  const int bq = blockIdx.x;
  const int b = bq / 384, q = bq % 384;
  const int j = threadIdx.x;
  const int w = j >> 6;
  __shared__ float red[6];
  float pb = 0.f;
  for (int h = 0; h < 4; ++h) {
    float s = (float)S[((size_t)((h * 64 + b) * 384 + q)) * 384 + j];
    float m = s;
#pragma unroll
    for (int o = 32; o; o >>= 1) m = fmaxf(m, __shfl_xor(m, o));
    if ((j & 63) == 0) red[w] = m;
    __syncthreads();
    m = fmaxf(fmaxf(fmaxf(red[0], red[1]), fmaxf(red[2], red[3])), fmaxf(red[4], red[5]));
    __syncthreads();
    float e = __expf(s - m);
    float l = e;
#pragma unroll
    for (int o = 32; o; o >>= 1) l += __shfl_xor(l, o);
    if ((j & 63) == 0) red[w] = l;
    __syncthreads();
    l = red[0] + red[1] + red[2] + red[3] + red[4] + red[5];
    __syncthreads();
    pb += e / l;
  }
  P[(size_t)bq * 384 + j] = (bf16)(0.25f * pb);
}

// ================= host side =================
template<int EPI, bool AF32, bool CF32>
static inline void rungemm(hipStream_t s,
    const void* A, int lda, const bf16* Bt, int ldb, void* C, int ldc,
    int M, int N, int K,
    const float* bias = nullptr, const float* cvec = nullptr,
    int Z = 1, int zdiv = 1,
    long sAh = 0, long sAb = 0, long sBh = 0, long sBb = 0, long sC = 0, long sBias = 0)
{
  dim3 grid(N / 128, M / 128, Z);
  gemm_kernel<EPI, AF32, CF32><<<grid, 256, 0, s>>>(A, lda, sAh, sAb, Bt, ldb, sBh, sBb, C, ldc, sC, K, zdiv, bias, cvec, sBias);
}

extern "C" void kernel_launch(void* const* d_in, const int* in_sizes, int n_in,
                              void* d_out, int out_size, void* d_ws, size_t ws_size,
                              hipStream_t stream)
{
  (void)in_sizes; (void)n_in; (void)out_size;
  const float* x      = (const float*)d_in[0];
  const float* ctx    = (const float*)d_in[1];
  const float* fg_W1  = (const float*)d_in[2];
  const float* fg_b1  = (const float*)d_in[3];
  const float* fg_Wc  = (const float*)d_in[4];
  const float* fg_W2  = (const float*)d_in[5];
  const float* fg_b2  = (const float*)d_in[6];
  const float* fg_Wg  = (const float*)d_in[7];
  const float* fg_bg  = (const float*)d_in[8];
  const float* fg_Ws  = (const float*)d_in[9];
  const float* fg_bs  = (const float*)d_in[10];
  const float* fg_lng = (const float*)d_in[11];
  const float* fg_lnb = (const float*)d_in[12];
  const float* sv_W1  = (const float*)d_in[13];
  const float* sv_b1  = (const float*)d_in[14];
  const float* sv_W2  = (const float*)d_in[15];
  const float* sv_b2  = (const float*)d_in[16];
  const float* sv_Wg  = (const float*)d_in[17];
  const float* sv_bg  = (const float*)d_in[18];
  const float* sv_lng = (const float*)d_in[19];
  const float* sv_lnb = (const float*)d_in[20];
  const float* en_W1  = (const float*)d_in[21];
  const float* en_b1  = (const float*)d_in[22];
  const float* en_Wc  = (const float*)d_in[23];
  const float* en_W2  = (const float*)d_in[24];
  const float* en_b2  = (const float*)d_in[25];
  const float* en_Wg  = (const float*)d_in[26];
  const float* en_bg  = (const float*)d_in[27];
  const float* en_lng = (const float*)d_in[28];
  const float* en_lnb = (const float*)d_in[29];
  const float* Wq     = (const float*)d_in[30];
  const float* Wk     = (const float*)d_in[31];
  const float* Wv     = (const float*)d_in[32];
  const float* Wo     = (const float*)d_in[33];

  // -------- workspace layout (bytes) --------
  static constexpr size_t OFF_FGW1WST = 0;                          // 384x3072 bf16
  static constexpr size_t OFF_FGWGPT  = OFF_FGW1WST + 2359296;      // 128x256 bf16
  static constexpr size_t OFF_FGW2C   = OFF_FGWGPT  + 65536;        // 256x256 bf16
  static constexpr size_t OFF_FGW2GT  = OFF_FGW2C   + 131072;       // 128x256 bf16
  static constexpr size_t OFF_BIAS384 = OFF_FGW2GT  + 65536;        // 384 f32
  static constexpr size_t OFF_FGBF    = OFF_BIAS384 + 1536;         // 128 f32
  static constexpr size_t OFF_SVW1T   = OFF_FGBF    + 512;          // 12x256x256 bf16
  static constexpr size_t OFF_SVWGT   = OFF_SVW1T   + 1572864;      // 12x512x256 bf16
  static constexpr size_t OFF_SVW2C   = OFF_SVWGT   + 3145728;      // 12x256x256 bf16
  static constexpr size_t OFF_SVW2GPT = OFF_SVW2C   + 1572864;      // 12x512x256 bf16 (row-permuted)
  static constexpr size_t OFF_SVBFP   = OFF_SVW2GPT + 3145728;      // 12x512 f32 (permuted)
  static constexpr size_t OFF_ENW1T   = OFF_SVBFP   + 24576;        // 256x256 bf16
  static constexpr size_t OFF_ENWGT   = OFF_ENW1T   + 131072;       // 512x256 bf16
  static constexpr size_t OFF_ENW2C   = OFF_ENWGT   + 262144;       // 256x256 bf16
  static constexpr size_t OFF_ENW2GPT = OFF_ENW2C   + 131072;       // 512x256 bf16 (row-permuted)
  static constexpr size_t OFF_ENBFP   = OFF_ENW2GPT + 262144;       // 512 f32 (permuted)
  static constexpr size_t OFF_WQKVT   = OFF_ENBFP   + 2048;         // 640x256 bf16
  static constexpr size_t OFF_WOT     = OFF_WQKVT   + 327680;       // 256x64 bf16
  static constexpr size_t OFF_CVECFG  = OFF_WOT     + 32768;        // 64x256 f32
  static constexpr size_t OFF_CVECEN  = OFF_CVECFG  + 65536;
  static constexpr size_t ARENA       = OFF_CVECEN  + 65536;        // = 13,365,248
  // arena overlays (offsets relative to ARENA):
  //  sv : sel@0(25.2M) selb@25165824(12.6M) wbuf@37748736(1.2M) H1G@38928384(50.3M) GATED@89260032(50.3M)
  //  fg : BUF384@38928384(18.9M) GPAD@57802752(6.3M) wbuf@37748736
  //  en : H1EN@38928384 GATEDEN@89260032 selb enr@139591680(12.6M)
  //  att: QKV@0(31.5M) Pbar@38928384(18.9M) Sbuf@64094208(75.5M) UT@64094208(12.6M, after Sbuf dead)
  static constexpr size_t WS_NEEDED = ARENA + 152174592;            // ~158 MB

  if (ws_size < WS_NEEDED) return;  // fail cleanly

  char* ws = (char*)d_ws;
  bf16*  fgW1WsT = (bf16*)(ws + OFF_FGW1WST);
  bf16*  fgWgPT  = (bf16*)(ws + OFF_FGWGPT);
  bf16*  fgW2C   = (bf16*)(ws + OFF_FGW2C);
  bf16*  fgW2gT  = (bf16*)(ws + OFF_FGW2GT);
  float* bias384 = (float*)(ws + OFF_BIAS384);
  float* fgBF    = (float*)(ws + OFF_FGBF);
  bf16*  svW1T   = (bf16*)(ws + OFF_SVW1T);
  bf16*  svWgT   = (bf16*)(ws + OFF_SVWGT);
  bf16*  svW2C   = (bf16*)(ws + OFF_SVW2C);
  bf16*  svW2gPT = (bf16*)(ws + OFF_SVW2GPT);
  float* svBFP   = (float*)(ws + OFF_SVBFP);
  bf16*  enW1T   = (bf16*)(ws + OFF_ENW1T);
  bf16*  enWgT   = (bf16*)(ws + OFF_ENWGT);
  bf16*  enW2C   = (bf16*)(ws + OFF_ENW2C);
  bf16*  enW2gPT = (bf16*)(ws + OFF_ENW2GPT);
  float* enBFP   = (float*)(ws + OFF_ENBFP);
  bf16*  WqkvT   = (bf16*)(ws + OFF_WQKVT);
  bf16*  WoT     = (bf16*)(ws + OFF_WOT);
  float* cvecFg  = (float*)(ws + OFF_CVECFG);
  float* cvecEn  = (float*)(ws + OFF_CVECEN);
  char*  ar      = ws + ARENA;
  float* sel     = (float*)(ar + 0);
  bf16*  selb    = (bf16*)(ar + 25165824);
  float* wbuf    = (float*)(ar + 37748736);
  bf16*  H1G     = (bf16*)(ar + 38928384);
  bf16*  BUF384  = (bf16*)(ar + 38928384);
  bf16*  GPAD    = (bf16*)(ar + 57802752);
  bf16*  H1EN    = (bf16*)(ar + 38928384);
  bf16*  GATED   = (bf16*)(ar + 89260032);
  bf16*  GATEDEN = (bf16*)(ar + 89260032);
  bf16*  enr     = (bf16*)(ar + 139591680);
  bf16*  QKV     = (bf16*)(ar + 0);
  bf16*  Pbar    = (bf16*)(ar + 38928384);
  bf16*  Sbuf    = (bf16*)(ar + 64094208);
  bf16*  UT      = (bf16*)(ar + 64094208);
  float* out     = (float*)d_out;

  // 1) weight prep
  prep_kernel<<<19010, 256, 0, stream>>>(fg_W1, fg_Ws, fg_W2, fg_Wg, fg_b1, fg_bs,
                                         sv_W1, sv_Wg, sv_W2, en_W1, en_Wg, en_W2,
                                         Wq, Wk, Wv, Wo,
                                         fgW1WsT, fgWgPT, fgW2C, bias384,
                                         svW1T, svWgT, svW2C, enW1T, enWgT, enW2C,
                                         WqkvT, WoT);
  // 2) fused biases (sv/en permuted) + context vectors
  biasfuse_kernel<<<27, 256, 0, stream>>>(fg_b2, fg_Wg, fg_bg, sv_b2, sv_Wg, sv_bg,
                                          en_b2, en_Wg, en_bg, fgBF, svBFP, enBFP);
  cvec_kernel<<<dim3(64, 2), 256, 0, stream>>>(ctx, fg_Wc, en_Wc, cvecFg, cvecEn);

  // 3) combined weights W2g[n][k2] = sum_k Wg[k][n]*W2[k2][k]; sv/en rows stored permuted
  rungemm<0,        false, false>(stream, fgWgPT, 256, fgW2C, 256, fgW2gT, 256, 128, 256, 256);
  rungemm<EPI_PERM, false, false>(stream, svWgT, 256, svW2C, 256, svW2gPT, 256, 512, 256, 256,
                                  nullptr, nullptr, 12, 12, 0, 131072, 0, 65536, 131072);
  rungemm<EPI_PERM, false, false>(stream, enWgT, 256, enW2C, 256, enW2gPT, 256, 512, 256, 256);

  // 4) flattened GRN: wide-tile fused [h1 | skip] GEMM (x read once), g GEMM, LN+softmax
  fgwide_kernel<<<384, 256, 0, stream>>>(x, fgW1WsT, BUF384, bias384, cvecFg);
  rungemm<EPI_BIAS, false, false>(stream, BUF384, 384, fgW2gT, 256, GPAD, 128, BTR, 128, 256, fgBF);
  lnsm12_kernel<<<96, 256, 0, stream>>>(BUF384, GPAD, fg_lng, fg_lnb, wbuf);

  // 5) per-variable GRNs, batched Z=4 (3 groups), gate fused in W2g epilogue
  for (int g = 0; g < 3; ++g) {
    rungemm<EPI_BIAS|EPI_ELU, true, false>(
        stream, x + g * 4 * 256, 3072, svW1T + (size_t)g * 4 * 65536, 256, H1G, 256, BTR, 256, 256,
        sv_b1 + g * 4 * 256, nullptr, 4, 4, 0, 256, 0, 65536, (long)BTR * 256, 256);
    rungemm<EPI_BIAS|EPI_GATE, false, false>(
        stream, H1G, 256, svW2gPT + (size_t)g * 4 * 131072, 256, GATED, 256, BTR, 512, 256,
        svBFP + g * 4 * 512, nullptr, 4, 4, 0, (long)BTR * 256, 0, 131072, (long)BTR * 256, 512);
    selacc4_kernel<<<BTR, 256, 0, stream>>>(GATED, x, wbuf, sv_lng, sv_lnb, sel, selb,
                                            g * 4, g == 0, g == 2);
  }

  // 6) enrichment GRN (gate fused)
  rungemm<EPI_BIAS|EPI_CVEC|EPI_ELU, false, false>(stream, selb, 256, enW1T, 256, H1EN, 256, BTR, 256, 256, en_b1, cvecEn);
  rungemm<EPI_BIAS|EPI_GATE, false, false>(stream, H1EN, 256, enW2gPT, 256, GATEDEN, 256, BTR, 512, 256, enBFP);
  enrln_kernel<<<BTR, 256, 0, stream>>>(GATEDEN, selb, en_lng, en_lnb, enr);

  // 7) attention
  rungemm<0, false, false>(stream, enr, 256, WqkvT, 256, QKV, 640, BTR, 640, 256);
  rungemm<EPI_ATTN, false, false>(stream, QKV, 640, QKV + 256, 640, Sbuf, 384, 384, 384, 64,
                                  nullptr, nullptr, 256, 64, 64, 245760L, 64, 245760L, 147456L);
  softmax_avg_kernel<<<BTR, 384, 0, stream>>>(Sbuf, Pbar);
  // UT[b][d][t] = sum_k Wo[k][d] * vp_b[t][k]  (direct transposed U; replaces U GEMM + transpose)
  rungemm<0, false, false>(stream, WoT, 64, QKV + 512, 640, UT, 384, 256, 384, 64,
                           nullptr, nullptr, 64, 64, 0, 0, 0, 245760L, 98304L);
  // out[b] = Pbar[b] @ UT[b]^T, batched over b -> f32 d_out
  rungemm<0, false, true>(stream, Pbar, 384, UT, 384, out, 256, 384, 256, 384,
                          nullptr, nullptr, 64, 1, 147456L, 0, 98304L, 0, 98304L);
}